// Round 1
// baseline (171.642 us; speedup 1.0000x reference)
//
#include <hip/hip_runtime.h>
#include <hip/hip_bf16.h>
#include <cstdint>

typedef __attribute__((ext_vector_type(8))) short sh8;   // 8 x bf16 bits
typedef __attribute__((ext_vector_type(4))) float f4;    // MFMA accumulator

#define T_SEQ 4096
#define DIMN  1024
#define NH    8
#define HDIM  128
#define NQKV  3072
#define ATTN_SCALE 0.12f

__device__ __forceinline__ ushort f2bf(float x) {
  __hip_bfloat16 b = __float2bfloat16(x);
  return *reinterpret_cast<ushort*>(&b);
}

// ---------------- fp32 -> bf16 convert (vectorized) ----------------
__global__ void k_f32_to_bf16(const float* __restrict__ in, ushort* __restrict__ out, int n4) {
  int i = blockIdx.x * blockDim.x + threadIdx.x;
  if (i >= n4) return;
  float4 v = reinterpret_cast<const float4*>(in)[i];
  ushort4 o;
  o.x = f2bf(v.x); o.y = f2bf(v.y); o.z = f2bf(v.z); o.w = f2bf(v.w);
  reinterpret_cast<ushort4*>(out)[i] = o;
}

// ---------------- doc_start: lower_bound over sorted docs ----------------
__global__ void k_docstart(const int* __restrict__ docs, int* __restrict__ dstart, int n) {
  int i = blockIdx.x * blockDim.x + threadIdx.x;
  if (i >= n) return;
  int d = docs[i];
  int lo = 0, hi = i;
  while (lo < hi) { int mid = (lo + hi) >> 1; if (docs[mid] < d) lo = mid + 1; else hi = mid; }
  dstart[i] = lo;
}

// ---------------- bf16 GEMM: C[M][N] = A[M][K] * B[N][K]^T ----------------
// 128x128 tile, BK=32, 4 waves (each 64x64 = 4x4 tiles of 16x16x32 MFMA)
__global__ __launch_bounds__(256) void k_gemm(const ushort* __restrict__ A,
                                              const ushort* __restrict__ B,
                                              float* __restrict__ C,
                                              int N, int K) {
  __shared__ ushort As[128][40];  // +8 pad: 2-way-max bank aliasing, keeps 16B align
  __shared__ ushort Bs[128][40];
  const int tid = threadIdx.x;
  const int lane = tid & 63;
  const int wave = tid >> 6;
  const int lr = lane & 15;
  const int lg = lane >> 4;
  const int wr = wave >> 1, wc = wave & 1;
  const int m0 = blockIdx.y * 128;
  const int n0 = blockIdx.x * 128;

  const f4 fzero = {0.f, 0.f, 0.f, 0.f};
  f4 acc[4][4];
#pragma unroll
  for (int i = 0; i < 4; ++i)
#pragma unroll
    for (int j = 0; j < 4; ++j) acc[i][j] = fzero;

  const int row0 = tid >> 2;        // 0..63
  const int row1 = row0 + 64;
  const int col8 = (tid & 3) * 8;   // 0,8,16,24

  for (int k0 = 0; k0 < K; k0 += 32) {
    __syncthreads();
    *reinterpret_cast<sh8*>(&As[row0][col8]) =
        *reinterpret_cast<const sh8*>(A + (size_t)(m0 + row0) * K + k0 + col8);
    *reinterpret_cast<sh8*>(&As[row1][col8]) =
        *reinterpret_cast<const sh8*>(A + (size_t)(m0 + row1) * K + k0 + col8);
    *reinterpret_cast<sh8*>(&Bs[row0][col8]) =
        *reinterpret_cast<const sh8*>(B + (size_t)(n0 + row0) * K + k0 + col8);
    *reinterpret_cast<sh8*>(&Bs[row1][col8]) =
        *reinterpret_cast<const sh8*>(B + (size_t)(n0 + row1) * K + k0 + col8);
    __syncthreads();

    sh8 af[4], bfr[4];
#pragma unroll
    for (int mt = 0; mt < 4; ++mt)
      af[mt] = *reinterpret_cast<const sh8*>(&As[wr * 64 + mt * 16 + lr][lg * 8]);
#pragma unroll
    for (int nt = 0; nt < 4; ++nt)
      bfr[nt] = *reinterpret_cast<const sh8*>(&Bs[wc * 64 + nt * 16 + lr][lg * 8]);
#pragma unroll
    for (int mt = 0; mt < 4; ++mt)
#pragma unroll
      for (int nt = 0; nt < 4; ++nt)
        acc[mt][nt] = __builtin_amdgcn_mfma_f32_16x16x32_bf16(af[mt], bfr[nt], acc[mt][nt], 0, 0, 0);
  }

#pragma unroll
  for (int mt = 0; mt < 4; ++mt) {
#pragma unroll
    for (int nt = 0; nt < 4; ++nt) {
      const int gcol = n0 + wc * 64 + nt * 16 + lr;
#pragma unroll
      for (int r = 0; r < 4; ++r) {
        const int grow = m0 + wr * 64 + mt * 16 + lg * 4 + r;
        C[(size_t)grow * N + gcol] = acc[mt][nt][r];
      }
    }
  }
}

// ---------------- fused RMSNorm + rotary + V-mix ----------------
// one wave per (t, h); lane handles dims d=lane and d=lane+64 (the rotary pair)
__global__ void k_fuse(const float* __restrict__ qkv, const float* __restrict__ ve,
                       const float* __restrict__ lambdas,
                       ushort* __restrict__ qh, ushort* __restrict__ kh, ushort* __restrict__ vh) {
  const int bid = blockIdx.x;
  const int t = bid >> 3;
  const int h = bid & 7;
  const int lane = threadIdx.x;  // 0..63
  const float* base = qkv + (size_t)t * NQKV + h * HDIM;
  float q1 = base[lane],        q2 = base[lane + 64];
  float k1 = base[1024 + lane], k2 = base[1024 + lane + 64];
  float v1 = base[2048 + lane], v2 = base[2048 + lane + 64];
  float sq = q1 * q1 + q2 * q2;
  float sk = k1 * k1 + k2 * k2;
#pragma unroll
  for (int m = 1; m < 64; m <<= 1) {
    sq += __shfl_xor(sq, m);
    sk += __shfl_xor(sk, m);
  }
  const float eps = 1.1920928955078125e-07f;
  float rq = rsqrtf(sq * (1.f / 128.f) + eps);
  float rk = rsqrtf(sk * (1.f / 128.f) + eps);
  q1 *= rq; q2 *= rq; k1 *= rk; k2 *= rk;
  float c = 1.f, s = 0.f;
  if (lane < 32) {
    float freq = exp2f(-10.f * (float)lane * (1.f / 31.f));  // (1/1024)^(lane/31)
    float th = (float)t * freq;
    sincosf(th, &s, &c);
  }
  float qo1 = q1 * c + q2 * s, qo2 = -q1 * s + q2 * c;
  float ko1 = k1 * c + k2 * s, ko2 = -k1 * s + k2 * c;
  const float l0 = lambdas[0], l1 = lambdas[1];
  const float* veb = ve + (size_t)t * DIMN + h * HDIM;
  float vo1 = l0 * v1 + l1 * veb[lane];
  float vo2 = l0 * v2 + l1 * veb[lane + 64];
  const size_t o = ((size_t)h * T_SEQ + t) * HDIM;
  qh[o + lane] = f2bf(qo1); qh[o + lane + 64] = f2bf(qo2);
  kh[o + lane] = f2bf(ko1); kh[o + lane + 64] = f2bf(ko2);
  vh[o + lane] = f2bf(vo1); vh[o + lane + 64] = f2bf(vo2);
}

// ---------------- flash attention with causal + doc mask ----------------
// block: 256 threads (4 waves), 64 q-rows (16/wave), KV blocks of 64
__global__ __launch_bounds__(256) void k_attn(const ushort* __restrict__ qh,
                                              const ushort* __restrict__ kh,
                                              const ushort* __restrict__ vh,
                                              const int* __restrict__ doc_start,
                                              ushort* __restrict__ y) {
  const int qb = blockIdx.x;
  const int h  = blockIdx.y;
  const int q0 = qb * 64;
  const int tid = threadIdx.x;
  const int wave = tid >> 6;
  const int lane = tid & 63;
  const int lr = lane & 15;
  const int lg = lane >> 4;

  __shared__ ushort Ks[64][136];   // K tile [j][d], padded
  __shared__ ushort Vt[128][72];   // V^T tile [d][j], padded
  __shared__ ushort Ps[4][16][72]; // per-wave P [row][j], padded

  const size_t hb = (size_t)h * T_SEQ * HDIM;

  sh8 qf[4];
  {
    const int qrow = q0 + wave * 16 + lr;
    const ushort* qp = qh + hb + (size_t)qrow * HDIM + lg * 8;
#pragma unroll
    for (int c = 0; c < 4; ++c) qf[c] = *reinterpret_cast<const sh8*>(qp + c * 32);
  }

  const f4 fzero = {0.f, 0.f, 0.f, 0.f};
  f4 o_acc[8];
#pragma unroll
  for (int i = 0; i < 8; ++i) o_acc[i] = fzero;
  float m_r[4], l_r[4];
#pragma unroll
  for (int r = 0; r < 4; ++r) { m_r[r] = -1e30f; l_r[r] = 0.f; }

  int i_g[4], ds_g[4];
#pragma unroll
  for (int r = 0; r < 4; ++r) {
    i_g[r] = q0 + wave * 16 + lg * 4 + r;
    ds_g[r] = doc_start[i_g[r]];
  }
  const int ds_hi = doc_start[q0 + 63];
  const int kb0 = doc_start[q0] >> 6;

  for (int kb = kb0; kb <= qb; ++kb) {
    const int k0 = kb * 64;
    __syncthreads();
    for (int c = tid; c < 1024; c += 256) {   // K tile: 64x128 in 8-elem chunks
      int row = c >> 4;
      int c8 = (c & 15) * 8;
      *reinterpret_cast<sh8*>(&Ks[row][c8]) =
          *reinterpret_cast<const sh8*>(kh + hb + (size_t)(k0 + row) * HDIM + c8);
    }
    for (int c = tid; c < 1024; c += 256) {   // V tile transposed
      int j = c >> 4;
      int d8 = (c & 15) * 8;
      sh8 vv = *reinterpret_cast<const sh8*>(vh + hb + (size_t)(k0 + j) * HDIM + d8);
#pragma unroll
      for (int e = 0; e < 8; ++e) Vt[d8 + e][j] = (ushort)vv[e];
    }
    __syncthreads();

    // S = Q K^T  (4 j-tiles of 16)
    f4 sacc[4];
#pragma unroll
    for (int jt = 0; jt < 4; ++jt) sacc[jt] = fzero;
#pragma unroll
    for (int jt = 0; jt < 4; ++jt)
#pragma unroll
      for (int c = 0; c < 4; ++c) {
        sh8 kf = *reinterpret_cast<const sh8*>(&Ks[jt * 16 + lr][c * 32 + lg * 8]);
        sacc[jt] = __builtin_amdgcn_mfma_f32_16x16x32_bf16(qf[c], kf, sacc[jt], 0, 0, 0);
      }

    const bool fullblk = (k0 + 64 <= q0) && (ds_hi <= k0);
    float p[4][4];
    float tmax[4] = {-1e30f, -1e30f, -1e30f, -1e30f};
#pragma unroll
    for (int jt = 0; jt < 4; ++jt) {
      const int jg = k0 + jt * 16 + lr;
#pragma unroll
      for (int r = 0; r < 4; ++r) {
        float s = sacc[jt][r] * ATTN_SCALE;
        bool valid = fullblk || ((jg <= i_g[r]) && (jg >= ds_g[r]));
        s = valid ? s : -1e30f;
        p[jt][r] = s;
        tmax[r] = fmaxf(tmax[r], s);
      }
    }
#pragma unroll
    for (int r = 0; r < 4; ++r)
#pragma unroll
      for (int mm = 1; mm < 16; mm <<= 1)
        tmax[r] = fmaxf(tmax[r], __shfl_xor(tmax[r], mm));

#pragma unroll
    for (int r = 0; r < 4; ++r) {
      float mnew = fmaxf(m_r[r], tmax[r]);
      float sc = __expf(m_r[r] - mnew);   // both -1e30 -> exp(0)=1 (fake rows erased later)
      m_r[r] = mnew;
      float sum = 0.f;
#pragma unroll
      for (int jt = 0; jt < 4; ++jt) {
        float pv = __expf(p[jt][r] - mnew);  // masked: -1e30 - finite -> 0
        p[jt][r] = pv;
        sum += pv;
      }
#pragma unroll
      for (int mm = 1; mm < 16; mm <<= 1) sum += __shfl_xor(sum, mm);
      l_r[r] = l_r[r] * sc + sum;
#pragma unroll
      for (int dt = 0; dt < 8; ++dt) o_acc[dt][r] *= sc;
    }

#pragma unroll
    for (int jt = 0; jt < 4; ++jt)
#pragma unroll
      for (int r = 0; r < 4; ++r)
        Ps[wave][lg * 4 + r][jt * 16 + lr] = f2bf(p[jt][r]);
    __syncthreads();  // P visible (uniform across waves)

#pragma unroll
    for (int ks = 0; ks < 2; ++ks) {
      sh8 pf = *reinterpret_cast<const sh8*>(&Ps[wave][lr][ks * 32 + lg * 8]);
#pragma unroll
      for (int dt = 0; dt < 8; ++dt) {
        sh8 vf = *reinterpret_cast<const sh8*>(&Vt[dt * 16 + lr][ks * 32 + lg * 8]);
        o_acc[dt] = __builtin_amdgcn_mfma_f32_16x16x32_bf16(pf, vf, o_acc[dt], 0, 0, 0);
      }
    }
  }

#pragma unroll
  for (int dt = 0; dt < 8; ++dt)
#pragma unroll
    for (int r = 0; r < 4; ++r) {
      const int trow = q0 + wave * 16 + lg * 4 + r;
      y[(size_t)trow * DIMN + h * HDIM + dt * 16 + lr] = f2bf(o_acc[dt][r] / l_r[r]);
    }
}

extern "C" void kernel_launch(void* const* d_in, const int* in_sizes, int n_in,
                              void* d_out, int out_size, void* d_ws, size_t ws_size,
                              hipStream_t stream) {
  const float* x    = (const float*)d_in[0];
  const float* ve   = (const float*)d_in[1];
  const float* qkvw = (const float*)d_in[2];
  const float* lam  = (const float*)d_in[3];
  const float* cpw  = (const float*)d_in[4];
  const int*   docs = (const int*)d_in[5];
  float* out = (float*)d_out;
  char* ws = (char*)d_ws;

  // workspace layout (bytes)
  float*  qkv  = (float*)(ws);                        // [0, 48MB)  fp32 qkv
  ushort* yb   = (ushort*)(ws);                       // overlay after qkv dead: 8MB
  ushort* cb   = (ushort*)(ws + (16ull << 20));       // overlay: 2MB
  ushort* xb   = (ushort*)(ws + (48ull << 20));       // 8MB
  ushort* wb   = (ushort*)(ws + (56ull << 20));       // 6MB
  ushort* qh   = (ushort*)(ws + (62ull << 20));       // 8MB
  ushort* kh   = (ushort*)(ws + (70ull << 20));       // 8MB
  ushort* vh   = (ushort*)(ws + (78ull << 20));       // 8MB
  int*  dstart = (int*)(ws + (86ull << 20));          // 16KB

  k_f32_to_bf16<<<(T_SEQ * DIMN / 4) / 256, 256, 0, stream>>>(x, xb, T_SEQ * DIMN / 4);
  k_f32_to_bf16<<<(NQKV * DIMN / 4) / 256, 256, 0, stream>>>(qkvw, wb, NQKV * DIMN / 4);

  k_gemm<<<dim3(NQKV / 128, T_SEQ / 128), 256, 0, stream>>>(xb, wb, qkv, NQKV, DIMN);

  k_fuse<<<T_SEQ * NH, 64, 0, stream>>>(qkv, ve, lam, qh, kh, vh);
  k_docstart<<<T_SEQ / 256, 256, 0, stream>>>(docs, dstart, T_SEQ);
  k_f32_to_bf16<<<(DIMN * DIMN / 4) / 256, 256, 0, stream>>>(cpw, cb, DIMN * DIMN / 4);

  k_attn<<<dim3(T_SEQ / 64, NH), 256, 0, stream>>>(qh, kh, vh, dstart, yb);

  k_gemm<<<dim3(DIMN / 128, T_SEQ / 128), 256, 0, stream>>>(yb, cb, out, DIMN, DIMN);
}

// Round 2
// 160.531 us; speedup vs baseline: 1.0692x; 1.0692x over previous
//
#include <hip/hip_runtime.h>
#include <hip/hip_bf16.h>
#include <cstdint>

typedef __attribute__((ext_vector_type(8))) short sh8;   // 8 x bf16 bits
typedef __attribute__((ext_vector_type(4))) float f4;    // MFMA accumulator

#define T_SEQ 4096
#define DIMN  1024
#define NH    8
#define HDIM  128
#define NQKV  3072
#define ATTN_SCALE 0.12f

__device__ __forceinline__ ushort f2bf(float x) {
  __hip_bfloat16 b = __float2bfloat16(x);
  return *reinterpret_cast<ushort*>(&b);
}
__device__ __forceinline__ float bf2f(ushort u) {
  uint v = ((uint)u) << 16;
  float f;
  __builtin_memcpy(&f, &v, 4);
  return f;
}

#define GLDS16(g, l) \
  __builtin_amdgcn_global_load_lds((const __attribute__((address_space(1))) void*)(g), \
                                   (__attribute__((address_space(3))) void*)(l), 16, 0, 0)

// ---------------- fp32 -> bf16 convert (vectorized) ----------------
__global__ void k_f32_to_bf16(const float* __restrict__ in, ushort* __restrict__ out, int n4) {
  int i = blockIdx.x * blockDim.x + threadIdx.x;
  if (i >= n4) return;
  float4 v = reinterpret_cast<const float4*>(in)[i];
  ushort4 o;
  o.x = f2bf(v.x); o.y = f2bf(v.y); o.z = f2bf(v.z); o.w = f2bf(v.w);
  reinterpret_cast<ushort4*>(out)[i] = o;
}

// ---------------- doc_start: lower_bound over sorted docs ----------------
__global__ void k_docstart(const int* __restrict__ docs, int* __restrict__ dstart, int n) {
  int i = blockIdx.x * blockDim.x + threadIdx.x;
  if (i >= n) return;
  int d = docs[i];
  int lo = 0, hi = i;
  while (lo < hi) { int mid = (lo + hi) >> 1; if (docs[mid] < d) lo = mid + 1; else hi = mid; }
  dstart[i] = lo;
}

// ---------------- bf16 GEMM: C[M][N] = A[M][K] * B[N][K]^T ----------------
// m97 structure: 128x128 tile, BK=64, global_load_lds(16B), XOR-swizzled LDS.
template <typename OT>
__global__ __launch_bounds__(256) void k_gemm(const ushort* __restrict__ A,
                                              const ushort* __restrict__ B,
                                              OT* __restrict__ C, int N, int K) {
  __shared__ ushort As[128 * 64];
  __shared__ ushort Bs[128 * 64];
  const int tid = threadIdx.x;
  const int lane = tid & 63;
  const int wave = tid >> 6;
  const int lr = lane & 15, lg = lane >> 4;
  const int wr = wave >> 1, wc = wave & 1;
  const int m0 = blockIdx.y * 128, n0 = blockIdx.x * 128;

  const f4 fzero = {0.f, 0.f, 0.f, 0.f};
  f4 acc[4][4];
#pragma unroll
  for (int i = 0; i < 4; ++i)
#pragma unroll
    for (int j = 0; j < 4; ++j) acc[i][j] = fzero;

  const int srow_base = wave * 8 + (lane >> 3);  // + i*32
  const int scg = lane & 7;

  for (int k0 = 0; k0 < K; k0 += 64) {
    __syncthreads();
#pragma unroll
    for (int i = 0; i < 4; ++i) {
      const int row = i * 32 + srow_base;
      const int cgl = scg ^ (row & 7);           // inverse-swizzled global source
      GLDS16(A + (size_t)(m0 + row) * K + k0 + cgl * 8, &As[i * 2048 + wave * 512]);
      GLDS16(B + (size_t)(n0 + row) * K + k0 + cgl * 8, &Bs[i * 2048 + wave * 512]);
    }
    __syncthreads();  // drains vmcnt

#pragma unroll
    for (int kk = 0; kk < 2; ++kk) {
      sh8 af[4], bfv[4];
#pragma unroll
      for (int mt = 0; mt < 4; ++mt) {
        const int row = wr * 64 + mt * 16 + lr;
        af[mt] = *reinterpret_cast<const sh8*>(&As[row * 64 + (((kk * 4 + lg) ^ (row & 7)) * 8)]);
      }
#pragma unroll
      for (int nt = 0; nt < 4; ++nt) {
        const int row = wc * 64 + nt * 16 + lr;
        bfv[nt] = *reinterpret_cast<const sh8*>(&Bs[row * 64 + (((kk * 4 + lg) ^ (row & 7)) * 8)]);
      }
#pragma unroll
      for (int mt = 0; mt < 4; ++mt)
#pragma unroll
        for (int nt = 0; nt < 4; ++nt)
          acc[mt][nt] = __builtin_amdgcn_mfma_f32_16x16x32_bf16(af[mt], bfv[nt], acc[mt][nt], 0, 0, 0);
    }
  }

#pragma unroll
  for (int mt = 0; mt < 4; ++mt)
#pragma unroll
    for (int nt = 0; nt < 4; ++nt) {
      const int gcol = n0 + wc * 64 + nt * 16 + lr;
#pragma unroll
      for (int r = 0; r < 4; ++r) {
        const int grow = m0 + wr * 64 + mt * 16 + lg * 4 + r;
        float v = acc[mt][nt][r];
        if constexpr (sizeof(OT) == 2)
          C[(size_t)grow * N + gcol] = (OT)f2bf(v);
        else
          C[(size_t)grow * N + gcol] = (OT)v;
      }
    }
}

// ---------------- fused RMSNorm + rotary + V-mix ----------------
// one wave per (t,h); lane l handles dims (2l, 2l+1); rotary partner = lane l^32
__global__ __launch_bounds__(64) void k_fuse(const ushort* __restrict__ qkvb,
                                             const float* __restrict__ ve,
                                             const float* __restrict__ lam,
                                             ushort* __restrict__ qh, ushort* __restrict__ kh,
                                             ushort* __restrict__ vh) {
  const int bid = blockIdx.x;
  const int t = bid >> 3, h = bid & 7;
  const int l = threadIdx.x;
  const ushort* base = qkvb + (size_t)t * NQKV + h * HDIM + 2 * l;
  uint qu = *reinterpret_cast<const uint*>(base);
  uint ku = *reinterpret_cast<const uint*>(base + 1024);
  uint vu = *reinterpret_cast<const uint*>(base + 2048);
  float q0 = bf2f((ushort)qu), q1 = bf2f((ushort)(qu >> 16));
  float k0 = bf2f((ushort)ku), k1 = bf2f((ushort)(ku >> 16));
  float v0 = bf2f((ushort)vu), v1 = bf2f((ushort)(vu >> 16));
  float sq = q0 * q0 + q1 * q1, sk = k0 * k0 + k1 * k1;
#pragma unroll
  for (int m = 1; m < 64; m <<= 1) { sq += __shfl_xor(sq, m); sk += __shfl_xor(sk, m); }
  const float eps = 1.1920928955078125e-07f;
  float rq = rsqrtf(sq * (1.f / 128.f) + eps);
  float rk = rsqrtf(sk * (1.f / 128.f) + eps);
  q0 *= rq; q1 *= rq; k0 *= rk; k1 *= rk;
  // rotary: freq idx f0=2*(l&31), f1=f0+1; rotate only f<32
  float c0 = 1.f, s0 = 0.f, c1 = 1.f, s1 = 0.f;
  if ((l & 31) < 16) {
    const int f0 = 2 * (l & 31);
    float fr0 = exp2f(-10.f * (float)f0 * (1.f / 31.f));
    float fr1 = exp2f(-10.f * (float)(f0 + 1) * (1.f / 31.f));
    sincosf((float)t * fr0, &s0, &c0);
    sincosf((float)t * fr1, &s1, &c1);
  }
  float qx0 = __shfl_xor(q0, 32), qx1 = __shfl_xor(q1, 32);
  float kx0 = __shfl_xor(k0, 32), kx1 = __shfl_xor(k1, 32);
  const float sgn = (l < 32) ? 1.f : -1.f;
  float qr0 = q0 * c0 + sgn * qx0 * s0;
  float qr1 = q1 * c1 + sgn * qx1 * s1;
  float kr0 = k0 * c0 + sgn * kx0 * s0;
  float kr1 = k1 * c1 + sgn * kx1 * s1;
  const float l0 = lam[0], l1 = lam[1];
  float2 vev = *reinterpret_cast<const float2*>(ve + (size_t)t * DIMN + h * HDIM + 2 * l);
  float vr0 = l0 * v0 + l1 * vev.x;
  float vr1 = l0 * v1 + l1 * vev.y;
  const size_t o = ((size_t)h * T_SEQ + t) * HDIM + 2 * l;
  *reinterpret_cast<uint*>(qh + o) = (uint)f2bf(qr0) | ((uint)f2bf(qr1) << 16);
  *reinterpret_cast<uint*>(kh + o) = (uint)f2bf(kr0) | ((uint)f2bf(kr1) << 16);
  *reinterpret_cast<uint*>(vh + o) = (uint)f2bf(vr0) | ((uint)f2bf(vr1) << 16);
}

// ---------------- V transpose: vh[h][t][d] -> vt[h][d][t] ----------------
__global__ __launch_bounds__(256) void k_vt(const ushort* __restrict__ vh, ushort* __restrict__ vt) {
  const int tb = blockIdx.x, db = blockIdx.y, h = blockIdx.z;
  __shared__ ushort L[64][68];
  const int tid = threadIdx.x;
  const int t0 = tb * 64, d0 = db * 64;
  const size_t ib = ((size_t)h * T_SEQ + t0) * HDIM + d0;
#pragma unroll
  for (int p = 0; p < 4; ++p) {
    const int row = p * 16 + (tid >> 4);
    const int c4 = (tid & 15) * 4;
    ushort4 v = *reinterpret_cast<const ushort4*>(vh + ib + (size_t)row * HDIM + c4);
    *reinterpret_cast<ushort4*>(&L[row][c4]) = v;
  }
  __syncthreads();
  const size_t ob = ((size_t)h * HDIM + d0) * T_SEQ + t0;
#pragma unroll
  for (int p = 0; p < 4; ++p) {
    const int drow = p * 16 + (tid >> 4);
    const int t4 = (tid & 15) * 4;
    ushort4 v;
    v.x = L[t4 + 0][drow]; v.y = L[t4 + 1][drow];
    v.z = L[t4 + 2][drow]; v.w = L[t4 + 3][drow];
    *reinterpret_cast<ushort4*>(vt + ob + (size_t)drow * T_SEQ + t4) = v;
  }
}

// ---------------- flash attention: 1 wave per 16 q-rows, no barriers ----------------
// K-frags and V^T-frags read directly from global (per-head K/V^T L2-resident,
// head pinned to XCD via bid&7). P via wave-private LDS slice.
__global__ __launch_bounds__(64) void k_attn(const ushort* __restrict__ qh,
                                             const ushort* __restrict__ kh,
                                             const ushort* __restrict__ vt,
                                             const int* __restrict__ doc_start,
                                             ushort* __restrict__ y) {
  const int bid = blockIdx.x;
  const int h = bid & 7;
  const int qw = bid >> 3;
  const int q0 = qw * 16;
  const int lane = threadIdx.x;
  const int lr = lane & 15, lg = lane >> 4;

  __shared__ ushort Ps[16][72];

  const ushort* Kh = kh + (size_t)h * T_SEQ * HDIM;
  const ushort* Vh = vt + (size_t)h * HDIM * T_SEQ;

  sh8 qf[4];
  {
    const ushort* qp = qh + ((size_t)h * T_SEQ + q0 + lr) * HDIM + lg * 8;
#pragma unroll
    for (int c = 0; c < 4; ++c) qf[c] = *reinterpret_cast<const sh8*>(qp + c * 32);
  }

  const f4 fzero = {0.f, 0.f, 0.f, 0.f};
  f4 o_acc[8];
#pragma unroll
  for (int i = 0; i < 8; ++i) o_acc[i] = fzero;
  float m_r[4], l_r[4];
#pragma unroll
  for (int r = 0; r < 4; ++r) { m_r[r] = -1e30f; l_r[r] = 0.f; }

  int i_g[4], ds_g[4];
#pragma unroll
  for (int r = 0; r < 4; ++r) {
    i_g[r] = q0 + lg * 4 + r;
    ds_g[r] = doc_start[i_g[r]];
  }
  const int ds_hi = doc_start[q0 + 15];
  const int kb0 = doc_start[q0] >> 6;
  const int qb = q0 >> 6;

  for (int kb = kb0; kb <= qb; ++kb) {
    const int k0 = kb * 64;

    // S = Q K^T : 4 j-subtiles x 4 d-slices
    f4 sacc[4];
#pragma unroll
    for (int jt = 0; jt < 4; ++jt) sacc[jt] = fzero;
#pragma unroll
    for (int jt = 0; jt < 4; ++jt) {
      const ushort* kp = Kh + (size_t)(k0 + jt * 16 + lr) * HDIM + lg * 8;
#pragma unroll
      for (int c = 0; c < 4; ++c) {
        sh8 kf = *reinterpret_cast<const sh8*>(kp + c * 32);
        sacc[jt] = __builtin_amdgcn_mfma_f32_16x16x32_bf16(qf[c], kf, sacc[jt], 0, 0, 0);
      }
    }

    const bool fullblk = (kb < qb) && (ds_hi <= k0);
    float p[4][4];
    float tmax[4] = {-1e30f, -1e30f, -1e30f, -1e30f};
#pragma unroll
    for (int jt = 0; jt < 4; ++jt) {
      const int jg = k0 + jt * 16 + lr;
#pragma unroll
      for (int r = 0; r < 4; ++r) {
        float s = sacc[jt][r] * ATTN_SCALE;
        bool valid = fullblk || ((jg <= i_g[r]) && (jg >= ds_g[r]));
        s = valid ? s : -1e30f;
        p[jt][r] = s;
        tmax[r] = fmaxf(tmax[r], s);
      }
    }
#pragma unroll
    for (int r = 0; r < 4; ++r)
#pragma unroll
      for (int mm = 1; mm < 16; mm <<= 1)
        tmax[r] = fmaxf(tmax[r], __shfl_xor(tmax[r], mm));

#pragma unroll
    for (int r = 0; r < 4; ++r) {
      float mnew = fmaxf(m_r[r], tmax[r]);
      float sc = __expf(m_r[r] - mnew);
      m_r[r] = mnew;
      float sum = 0.f;
#pragma unroll
      for (int jt = 0; jt < 4; ++jt) {
        float pv = __expf(p[jt][r] - mnew);
        p[jt][r] = pv;
        sum += pv;
      }
#pragma unroll
      for (int mm = 1; mm < 16; mm <<= 1) sum += __shfl_xor(sum, mm);
      l_r[r] = l_r[r] * sc + sum;
#pragma unroll
      for (int dt = 0; dt < 8; ++dt) o_acc[dt][r] *= sc;
    }

#pragma unroll
    for (int jt = 0; jt < 4; ++jt)
#pragma unroll
      for (int r = 0; r < 4; ++r)
        Ps[lg * 4 + r][jt * 16 + lr] = f2bf(p[jt][r]);
    // wave-private: compiler inserts lgkmcnt waits, no barrier needed

#pragma unroll
    for (int ks = 0; ks < 2; ++ks) {
      sh8 pf = *reinterpret_cast<const sh8*>(&Ps[lr][ks * 32 + lg * 8]);
#pragma unroll
      for (int dt = 0; dt < 8; ++dt) {
        sh8 vf = *reinterpret_cast<const sh8*>(Vh + (size_t)(dt * 16 + lr) * T_SEQ + k0 + ks * 32 + lg * 8);
        o_acc[dt] = __builtin_amdgcn_mfma_f32_16x16x32_bf16(pf, vf, o_acc[dt], 0, 0, 0);
      }
    }
  }

#pragma unroll
  for (int dt = 0; dt < 8; ++dt)
#pragma unroll
    for (int r = 0; r < 4; ++r) {
      const int trow = q0 + lg * 4 + r;
      y[(size_t)trow * DIMN + h * HDIM + dt * 16 + lr] = f2bf(o_acc[dt][r] / l_r[r]);
    }
}

extern "C" void kernel_launch(void* const* d_in, const int* in_sizes, int n_in,
                              void* d_out, int out_size, void* d_ws, size_t ws_size,
                              hipStream_t stream) {
  const float* x    = (const float*)d_in[0];
  const float* ve   = (const float*)d_in[1];
  const float* qkvw = (const float*)d_in[2];
  const float* lam  = (const float*)d_in[3];
  const float* cpw  = (const float*)d_in[4];
  const int*   docs = (const int*)d_in[5];
  float* out = (float*)d_out;
  char* ws = (char*)d_ws;

  // workspace layout (bytes)
  ushort* qkvb = (ushort*)(ws);                    // 24MB  [0,24)
  ushort* xb   = (ushort*)(ws + (24ull << 20));    // 8MB   [24,32)
  ushort* wb   = (ushort*)(ws + (32ull << 20));    // 6MB   [32,38)
  ushort* cb   = (ushort*)(ws + (38ull << 20));    // 2MB   [38,40)
  ushort* qh   = (ushort*)(ws + (40ull << 20));    // 8MB   [40,48)
  ushort* kh   = (ushort*)(ws + (48ull << 20));    // 8MB   [48,56)
  ushort* vh   = (ushort*)(ws + (56ull << 20));    // 8MB   [56,64)
  ushort* vt   = (ushort*)(ws + (64ull << 20));    // 8MB   [64,72)
  ushort* yb   = (ushort*)(ws + (72ull << 20));    // 8MB   [72,80)
  int*  dstart = (int*)(ws + (80ull << 20));       // 16KB

  k_f32_to_bf16<<<(T_SEQ * DIMN / 4) / 256, 256, 0, stream>>>(x, xb, T_SEQ * DIMN / 4);
  k_f32_to_bf16<<<(NQKV * DIMN / 4) / 256, 256, 0, stream>>>(qkvw, wb, NQKV * DIMN / 4);
  k_f32_to_bf16<<<(DIMN * DIMN / 4) / 256, 256, 0, stream>>>(cpw, cb, DIMN * DIMN / 4);

  k_gemm<ushort><<<dim3(NQKV / 128, T_SEQ / 128), 256, 0, stream>>>(xb, wb, qkvb, NQKV, DIMN);

  k_fuse<<<T_SEQ * NH, 64, 0, stream>>>(qkvb, ve, lam, qh, kh, vh);
  k_docstart<<<T_SEQ / 256, 256, 0, stream>>>(docs, dstart, T_SEQ);
  k_vt<<<dim3(T_SEQ / 64, HDIM / 64, NH), 256, 0, stream>>>(vh, vt);

  k_attn<<<T_SEQ / 16 * NH, 64, 0, stream>>>(qh, kh, vt, dstart, yb);

  k_gemm<float><<<dim3(DIMN / 128, T_SEQ / 128), 256, 0, stream>>>(yb, cb, out, DIMN, DIMN);
}

// Round 3
// 117.864 us; speedup vs baseline: 1.4563x; 1.3620x over previous
//
#include <hip/hip_runtime.h>
#include <hip/hip_bf16.h>
#include <cstdint>

typedef __attribute__((ext_vector_type(8))) short sh8;   // 8 x bf16 bits
typedef __attribute__((ext_vector_type(4))) float f4;    // MFMA accumulator

#define T_SEQ 4096
#define DIMN  1024
#define NH    8
#define HDIM  128
#define NQKV  3072
#define ATTN_SCALE 0.12f

__device__ __forceinline__ ushort f2bf(float x) {
  __hip_bfloat16 b = __float2bfloat16(x);
  return *reinterpret_cast<ushort*>(&b);
}
__device__ __forceinline__ float bf2f(ushort u) {
  uint v = ((uint)u) << 16;
  float f;
  __builtin_memcpy(&f, &v, 4);
  return f;
}

#define GLDS16(g, l) \
  __builtin_amdgcn_global_load_lds((const __attribute__((address_space(1))) void*)(g), \
                                   (__attribute__((address_space(3))) void*)(l), 16, 0, 0)

// ---------------- fp32 -> bf16 convert (vectorized) ----------------
__global__ void k_f32_to_bf16(const float* __restrict__ in, ushort* __restrict__ out, int n4) {
  int i = blockIdx.x * blockDim.x + threadIdx.x;
  if (i >= n4) return;
  float4 v = reinterpret_cast<const float4*>(in)[i];
  ushort4 o;
  o.x = f2bf(v.x); o.y = f2bf(v.y); o.z = f2bf(v.z); o.w = f2bf(v.w);
  reinterpret_cast<ushort4*>(out)[i] = o;
}

// ---------------- doc_start: lower_bound over sorted docs ----------------
__global__ void k_docstart(const int* __restrict__ docs, int* __restrict__ dstart, int n) {
  int i = blockIdx.x * blockDim.x + threadIdx.x;
  if (i >= n) return;
  int d = docs[i];
  int lo = 0, hi = i;
  while (lo < hi) { int mid = (lo + hi) >> 1; if (docs[mid] < d) lo = mid + 1; else hi = mid; }
  dstart[i] = lo;
}

// ---------------- bf16 GEMM: C[M][N] = A[M][K] * B[N][K]^T ----------------
// m97 structure: 128x128 tile, BK=64, global_load_lds(16B), XOR-swizzled LDS.
template <typename OT>
__global__ __launch_bounds__(256) void k_gemm(const ushort* __restrict__ A,
                                              const ushort* __restrict__ B,
                                              OT* __restrict__ C, int N, int K) {
  __shared__ ushort As[128 * 64];
  __shared__ ushort Bs[128 * 64];
  const int tid = threadIdx.x;
  const int lane = tid & 63;
  const int wave = tid >> 6;
  const int lr = lane & 15, lg = lane >> 4;
  const int wr = wave >> 1, wc = wave & 1;
  const int m0 = blockIdx.y * 128, n0 = blockIdx.x * 128;

  const f4 fzero = {0.f, 0.f, 0.f, 0.f};
  f4 acc[4][4];
#pragma unroll
  for (int i = 0; i < 4; ++i)
#pragma unroll
    for (int j = 0; j < 4; ++j) acc[i][j] = fzero;

  const int srow_base = wave * 8 + (lane >> 3);  // + i*32
  const int scg = lane & 7;

  for (int k0 = 0; k0 < K; k0 += 64) {
    __syncthreads();
#pragma unroll
    for (int i = 0; i < 4; ++i) {
      const int row = i * 32 + srow_base;
      const int cgl = scg ^ (row & 7);           // inverse-swizzled global source
      GLDS16(A + (size_t)(m0 + row) * K + k0 + cgl * 8, &As[i * 2048 + wave * 512]);
      GLDS16(B + (size_t)(n0 + row) * K + k0 + cgl * 8, &Bs[i * 2048 + wave * 512]);
    }
    __syncthreads();  // drains vmcnt

#pragma unroll
    for (int kk = 0; kk < 2; ++kk) {
      sh8 af[4], bfv[4];
#pragma unroll
      for (int mt = 0; mt < 4; ++mt) {
        const int row = wr * 64 + mt * 16 + lr;
        af[mt] = *reinterpret_cast<const sh8*>(&As[row * 64 + (((kk * 4 + lg) ^ (row & 7)) * 8)]);
      }
#pragma unroll
      for (int nt = 0; nt < 4; ++nt) {
        const int row = wc * 64 + nt * 16 + lr;
        bfv[nt] = *reinterpret_cast<const sh8*>(&Bs[row * 64 + (((kk * 4 + lg) ^ (row & 7)) * 8)]);
      }
#pragma unroll
      for (int mt = 0; mt < 4; ++mt)
#pragma unroll
        for (int nt = 0; nt < 4; ++nt)
          acc[mt][nt] = __builtin_amdgcn_mfma_f32_16x16x32_bf16(af[mt], bfv[nt], acc[mt][nt], 0, 0, 0);
    }
  }

#pragma unroll
  for (int mt = 0; mt < 4; ++mt)
#pragma unroll
    for (int nt = 0; nt < 4; ++nt) {
      const int gcol = n0 + wc * 64 + nt * 16 + lr;
#pragma unroll
      for (int r = 0; r < 4; ++r) {
        const int grow = m0 + wr * 64 + mt * 16 + lg * 4 + r;
        float v = acc[mt][nt][r];
        if constexpr (sizeof(OT) == 2)
          C[(size_t)grow * N + gcol] = (OT)f2bf(v);
        else
          C[(size_t)grow * N + gcol] = (OT)v;
      }
    }
}

// ---------------- fused RMSNorm + rotary + V-mix ----------------
__global__ __launch_bounds__(64) void k_fuse(const ushort* __restrict__ qkvb,
                                             const float* __restrict__ ve,
                                             const float* __restrict__ lam,
                                             ushort* __restrict__ qh, ushort* __restrict__ kh,
                                             ushort* __restrict__ vh) {
  const int bid = blockIdx.x;
  const int t = bid >> 3, h = bid & 7;
  const int l = threadIdx.x;
  const ushort* base = qkvb + (size_t)t * NQKV + h * HDIM + 2 * l;
  uint qu = *reinterpret_cast<const uint*>(base);
  uint ku = *reinterpret_cast<const uint*>(base + 1024);
  uint vu = *reinterpret_cast<const uint*>(base + 2048);
  float q0 = bf2f((ushort)qu), q1 = bf2f((ushort)(qu >> 16));
  float k0 = bf2f((ushort)ku), k1 = bf2f((ushort)(ku >> 16));
  float v0 = bf2f((ushort)vu), v1 = bf2f((ushort)(vu >> 16));
  float sq = q0 * q0 + q1 * q1, sk = k0 * k0 + k1 * k1;
#pragma unroll
  for (int m = 1; m < 64; m <<= 1) { sq += __shfl_xor(sq, m); sk += __shfl_xor(sk, m); }
  const float eps = 1.1920928955078125e-07f;
  float rq = rsqrtf(sq * (1.f / 128.f) + eps);
  float rk = rsqrtf(sk * (1.f / 128.f) + eps);
  q0 *= rq; q1 *= rq; k0 *= rk; k1 *= rk;
  float c0 = 1.f, s0 = 0.f, c1 = 1.f, s1 = 0.f;
  if ((l & 31) < 16) {
    const int f0 = 2 * (l & 31);
    float fr0 = exp2f(-10.f * (float)f0 * (1.f / 31.f));
    float fr1 = exp2f(-10.f * (float)(f0 + 1) * (1.f / 31.f));
    sincosf((float)t * fr0, &s0, &c0);
    sincosf((float)t * fr1, &s1, &c1);
  }
  float qx0 = __shfl_xor(q0, 32), qx1 = __shfl_xor(q1, 32);
  float kx0 = __shfl_xor(k0, 32), kx1 = __shfl_xor(k1, 32);
  const float sgn = (l < 32) ? 1.f : -1.f;
  float qr0 = q0 * c0 + sgn * qx0 * s0;
  float qr1 = q1 * c1 + sgn * qx1 * s1;
  float kr0 = k0 * c0 + sgn * kx0 * s0;
  float kr1 = k1 * c1 + sgn * kx1 * s1;
  const float l0 = lam[0], l1 = lam[1];
  float2 vev = *reinterpret_cast<const float2*>(ve + (size_t)t * DIMN + h * HDIM + 2 * l);
  float vr0 = l0 * v0 + l1 * vev.x;
  float vr1 = l0 * v1 + l1 * vev.y;
  const size_t o = ((size_t)h * T_SEQ + t) * HDIM + 2 * l;
  *reinterpret_cast<uint*>(qh + o) = (uint)f2bf(qr0) | ((uint)f2bf(qr1) << 16);
  *reinterpret_cast<uint*>(kh + o) = (uint)f2bf(kr0) | ((uint)f2bf(kr1) << 16);
  *reinterpret_cast<uint*>(vh + o) = (uint)f2bf(vr0) | ((uint)f2bf(vr1) << 16);
}

// ---------------- V transpose: vh[h][t][d] -> vt[h][d][t] ----------------
__global__ __launch_bounds__(256) void k_vt(const ushort* __restrict__ vh, ushort* __restrict__ vt) {
  const int tb = blockIdx.x, db = blockIdx.y, h = blockIdx.z;
  __shared__ ushort L[64][68];
  const int tid = threadIdx.x;
  const int t0 = tb * 64, d0 = db * 64;
  const size_t ib = ((size_t)h * T_SEQ + t0) * HDIM + d0;
#pragma unroll
  for (int p = 0; p < 4; ++p) {
    const int row = p * 16 + (tid >> 4);
    const int c4 = (tid & 15) * 4;
    ushort4 v = *reinterpret_cast<const ushort4*>(vh + ib + (size_t)row * HDIM + c4);
    *reinterpret_cast<ushort4*>(&L[row][c4]) = v;
  }
  __syncthreads();
  const size_t ob = ((size_t)h * HDIM + d0) * T_SEQ + t0;
#pragma unroll
  for (int p = 0; p < 4; ++p) {
    const int drow = p * 16 + (tid >> 4);
    const int t4 = (tid & 15) * 4;
    ushort4 v;
    v.x = L[t4 + 0][drow]; v.y = L[t4 + 1][drow];
    v.z = L[t4 + 2][drow]; v.w = L[t4 + 3][drow];
    *reinterpret_cast<ushort4*>(vt + ob + (size_t)drow * T_SEQ + t4) = v;
  }
}

// ---------------- flash attention: 4 waves, 64 q-rows, LDS-staged KV ----------------
// 2-phase pipeline (stage t+1 during compute t), double-buffered K and V^T,
// XOR-swizzled LDS, swapped QK^T (mfma(K,Q)) for in-register softmax.
__global__ __launch_bounds__(256) void k_attn(const ushort* __restrict__ qh,
                                              const ushort* __restrict__ kh,
                                              const ushort* __restrict__ vt,
                                              const int* __restrict__ doc_start,
                                              ushort* __restrict__ y) {
  const int h  = blockIdx.x;          // head pinned to XCD (linear wg id % 8 == h)
  const int qb = blockIdx.y;          // 64-row q tile
  const int q0 = qb * 64;
  const int tid  = threadIdx.x;
  const int wave = tid >> 6;
  const int lane = tid & 63;
  const int lr = lane & 15, lg = lane >> 4;

  __shared__ ushort Ks[2][64 * 128];   // [buf][j][d]   rows 256B, chunk-swizzled
  __shared__ ushort Vs[2][128 * 64];   // [buf][d][t]   rows 128B, chunk-swizzled
  __shared__ ushort Ps[4][16 * 64];    // [wave][i][j]  rows 128B, chunk-swizzled

  const ushort* Kg = kh + (size_t)h * T_SEQ * HDIM;
  const ushort* Vg = vt + (size_t)h * HDIM * T_SEQ;

  // Q fragment (B operand of swapped mfma) — wave's 16 rows, from global (L2)
  const int i_me = q0 + wave * 16 + lr;     // q-row this lane owns for softmax
  sh8 qf[4];
  {
    const ushort* qp = qh + ((size_t)h * T_SEQ + i_me) * HDIM + lg * 8;
#pragma unroll
    for (int c = 0; c < 4; ++c) qf[c] = *reinterpret_cast<const sh8*>(qp + c * 32);
  }
  const int ds_me = doc_start[i_me];
  const int ds_hi = doc_start[q0 + 63];
  const int kb0   = doc_start[q0] >> 6;

  const f4 fzero = {0.f, 0.f, 0.f, 0.f};
  f4 o_acc[8];
#pragma unroll
  for (int i = 0; i < 8; ++i) o_acc[i] = fzero;
  float m_me = -1e30f, l_me = 0.f;

  // cooperative stage of one KV tile into buffer b (8 x GLDS16 per thread)
  auto STAGE = [&](int b, int k0) {
#pragma unroll
    for (int p = 0; p < 4; ++p) {                 // K: 64 rows x 16 chunks
      const int c = p * 256 + tid;
      const int row = c >> 4, cc = c & 15;
      GLDS16(Kg + (size_t)(k0 + row) * HDIM + (cc ^ (row & 7)) * 8,
             &Ks[b][(p * 256 + wave * 64) * 8]);
    }
#pragma unroll
    for (int p = 0; p < 4; ++p) {                 // V^T: 128 rows x 8 chunks
      const int c = p * 256 + tid;
      const int d = c >> 3, cc = c & 7;
      GLDS16(Vg + (size_t)d * T_SEQ + k0 + (cc ^ (d & 7)) * 8,
             &Vs[b][(p * 256 + wave * 64) * 8]);
    }
  };

  int cur = 0;
  STAGE(0, kb0 * 64);

  const int sw = (lr & 7) << 4;  // XOR swizzle for rows with row&7 == lr&7

  for (int kb = kb0; kb <= qb; ++kb) {
    const int k0 = kb * 64;
    __syncthreads();                       // drains vmcnt: buf[cur] ready
    if (kb < qb) STAGE(cur ^ 1, k0 + 64);  // prefetch next tile

    const char* Kb = (const char*)&Ks[cur][0];
    const char* Vb = (const char*)&Vs[cur][0];
    char* Pw = (char*)&Ps[wave][0];

    // S^T = K Q^T : lane holds S[q=lr][j=k0+jt*16+lg*4+r]
    f4 sacc[4];
#pragma unroll
    for (int jt = 0; jt < 4; ++jt) sacc[jt] = fzero;
#pragma unroll
    for (int jt = 0; jt < 4; ++jt)
#pragma unroll
      for (int c = 0; c < 4; ++c) {
        sh8 kf = *reinterpret_cast<const sh8*>(Kb + (jt * 16 + lr) * 256 + ((c * 64 + lg * 16) ^ sw));
        sacc[jt] = __builtin_amdgcn_mfma_f32_16x16x32_bf16(kf, qf[c], sacc[jt], 0, 0, 0);
      }

    const bool fullblk = (kb < qb) && (ds_hi <= k0);
    float p[4][4];
#pragma unroll
    for (int jt = 0; jt < 4; ++jt)
#pragma unroll
      for (int r = 0; r < 4; ++r) {
        float s = sacc[jt][r] * ATTN_SCALE;
        const int j = k0 + jt * 16 + lg * 4 + r;
        bool valid = fullblk || ((j <= i_me) && (j >= ds_me));
        p[jt][r] = valid ? s : -1e30f;
      }
    // in-register row max (16 values) + 2-shfl lg-reduce
    float tm = -1e30f;
#pragma unroll
    for (int jt = 0; jt < 4; ++jt) {
      float a = fmaxf(p[jt][0], p[jt][1]), b = fmaxf(p[jt][2], p[jt][3]);
      tm = fmaxf(tm, fmaxf(a, b));
    }
    tm = fmaxf(tm, __shfl_xor(tm, 16));
    tm = fmaxf(tm, __shfl_xor(tm, 32));
    const float mnew = fmaxf(m_me, tm);
    const float sc = __expf(m_me - mnew);   // both -1e30 -> 1 (junk erased at first valid tile)
    m_me = mnew;
    float rs = 0.f;
#pragma unroll
    for (int jt = 0; jt < 4; ++jt)
#pragma unroll
      for (int r = 0; r < 4; ++r) {
        float pv = __expf(p[jt][r] - mnew);
        p[jt][r] = pv;
        rs += pv;
      }
    rs += __shfl_xor(rs, 16);
    rs += __shfl_xor(rs, 32);
    l_me = l_me * sc + rs;

    // P -> LDS (bf16, swizzled rows)
#pragma unroll
    for (int jt = 0; jt < 4; ++jt) {
      uint2 u;
      u.x = (uint)f2bf(p[jt][0]) | ((uint)f2bf(p[jt][1]) << 16);
      u.y = (uint)f2bf(p[jt][2]) | ((uint)f2bf(p[jt][3]) << 16);
      *reinterpret_cast<uint2*>(Pw + lr * 128 + ((jt * 32 + lg * 8) ^ sw)) = u;
    }

    // rescale o_acc rows (row = lg*4+rr) using sc from owner lanes
    float sco[4];
#pragma unroll
    for (int rr = 0; rr < 4; ++rr) sco[rr] = __shfl(sc, lg * 4 + rr);
#pragma unroll
    for (int dt = 0; dt < 8; ++dt)
#pragma unroll
      for (int rr = 0; rr < 4; ++rr) o_acc[dt][rr] *= sco[rr];

    // PV: O += P V
#pragma unroll
    for (int ks = 0; ks < 2; ++ks) {
      sh8 pa = *reinterpret_cast<const sh8*>(Pw + lr * 128 + ((ks * 64 + lg * 16) ^ sw));
#pragma unroll
      for (int dt = 0; dt < 8; ++dt) {
        sh8 vf = *reinterpret_cast<const sh8*>(Vb + (dt * 16 + lr) * 128 + ((ks * 64 + lg * 16) ^ sw));
        o_acc[dt] = __builtin_amdgcn_mfma_f32_16x16x32_bf16(pa, vf, o_acc[dt], 0, 0, 0);
      }
    }

    __builtin_amdgcn_s_barrier();          // all waves done reading buf[cur]
    cur ^= 1;
  }

  // epilogue: divide by l (redistributed to o_acc row owners) and store
  float lo[4];
#pragma unroll
  for (int rr = 0; rr < 4; ++rr) lo[rr] = __shfl(l_me, lg * 4 + rr);
#pragma unroll
  for (int dt = 0; dt < 8; ++dt)
#pragma unroll
    for (int rr = 0; rr < 4; ++rr) {
      const int trow = q0 + wave * 16 + lg * 4 + rr;
      y[(size_t)trow * DIMN + h * HDIM + dt * 16 + lr] = f2bf(o_acc[dt][rr] / lo[rr]);
    }
}

extern "C" void kernel_launch(void* const* d_in, const int* in_sizes, int n_in,
                              void* d_out, int out_size, void* d_ws, size_t ws_size,
                              hipStream_t stream) {
  const float* x    = (const float*)d_in[0];
  const float* ve   = (const float*)d_in[1];
  const float* qkvw = (const float*)d_in[2];
  const float* lam  = (const float*)d_in[3];
  const float* cpw  = (const float*)d_in[4];
  const int*   docs = (const int*)d_in[5];
  float* out = (float*)d_out;
  char* ws = (char*)d_ws;

  // workspace layout (bytes)
  ushort* qkvb = (ushort*)(ws);                    // 24MB  [0,24)
  ushort* xb   = (ushort*)(ws + (24ull << 20));    // 8MB   [24,32)
  ushort* wb   = (ushort*)(ws + (32ull << 20));    // 6MB   [32,38)
  ushort* cb   = (ushort*)(ws + (38ull << 20));    // 2MB   [38,40)
  ushort* qh   = (ushort*)(ws + (40ull << 20));    // 8MB   [40,48)
  ushort* kh   = (ushort*)(ws + (48ull << 20));    // 8MB   [48,56)
  ushort* vh   = (ushort*)(ws + (56ull << 20));    // 8MB   [56,64)
  ushort* vt   = (ushort*)(ws + (64ull << 20));    // 8MB   [64,72)
  ushort* yb   = (ushort*)(ws + (72ull << 20));    // 8MB   [72,80)
  int*  dstart = (int*)(ws + (80ull << 20));       // 16KB

  k_f32_to_bf16<<<(T_SEQ * DIMN / 4) / 256, 256, 0, stream>>>(x, xb, T_SEQ * DIMN / 4);
  k_f32_to_bf16<<<(NQKV * DIMN / 4) / 256, 256, 0, stream>>>(qkvw, wb, NQKV * DIMN / 4);
  k_f32_to_bf16<<<(DIMN * DIMN / 4) / 256, 256, 0, stream>>>(cpw, cb, DIMN * DIMN / 4);

  k_gemm<ushort><<<dim3(NQKV / 128, T_SEQ / 128), 256, 0, stream>>>(xb, wb, qkvb, NQKV, DIMN);

  k_fuse<<<T_SEQ * NH, 64, 0, stream>>>(qkvb, ve, lam, qh, kh, vh);
  k_docstart<<<T_SEQ / 256, 256, 0, stream>>>(docs, dstart, T_SEQ);
  k_vt<<<dim3(T_SEQ / 64, HDIM / 64, NH), 256, 0, stream>>>(vh, vt);

  k_attn<<<dim3(NH, T_SEQ / 64), 256, 0, stream>>>(qh, kh, vt, dstart, yb);

  k_gemm<float><<<dim3(DIMN / 128, T_SEQ / 128), 256, 0, stream>>>(yb, cb, out, DIMN, DIMN);
}

// Round 4
// 117.717 us; speedup vs baseline: 1.4581x; 1.0012x over previous
//
#include <hip/hip_runtime.h>
#include <hip/hip_bf16.h>
#include <cstdint>

typedef __attribute__((ext_vector_type(8))) short sh8;   // 8 x bf16 bits
typedef __attribute__((ext_vector_type(4))) float f4;    // MFMA accumulator

#define T_SEQ 4096
#define DIMN  1024
#define NH    8
#define HDIM  128
#define NQKV  3072
#define ATTN_SCALE 0.12f

__device__ __forceinline__ ushort f2bf(float x) {
  __hip_bfloat16 b = __float2bfloat16(x);
  return *reinterpret_cast<ushort*>(&b);
}
__device__ __forceinline__ float bf2f(ushort u) {
  uint v = ((uint)u) << 16;
  float f;
  __builtin_memcpy(&f, &v, 4);
  return f;
}

#define GLDS16(g, l) \
  __builtin_amdgcn_global_load_lds((const __attribute__((address_space(1))) void*)(g), \
                                   (__attribute__((address_space(3))) void*)(l), 16, 0, 0)

template <int N>
__device__ __forceinline__ void wait_vmcnt() {
  if constexpr (N == 0)      asm volatile("s_waitcnt vmcnt(0)" ::: "memory");
  else if constexpr (N == 4) asm volatile("s_waitcnt vmcnt(4)" ::: "memory");
  else if constexpr (N == 6) asm volatile("s_waitcnt vmcnt(6)" ::: "memory");
  else if constexpr (N == 8) asm volatile("s_waitcnt vmcnt(8)" ::: "memory");
  __builtin_amdgcn_sched_barrier(0);
}

// ---------------- prep: 3 fp32->bf16 converts + doc_start ----------------
__global__ __launch_bounds__(256) void k_prep(const float* __restrict__ x,
                                              const float* __restrict__ qw,
                                              const float* __restrict__ cw,
                                              ushort* __restrict__ xb, ushort* __restrict__ wb,
                                              ushort* __restrict__ cbuf,
                                              const int* __restrict__ docs, int* __restrict__ dstart) {
  const int b = blockIdx.x;
  if (b < 8192) {
    const int i = b * 256 + threadIdx.x;  // float4 index over concatenated buffers
    const float* src;
    ushort* dst;
    int j;
    if (i < 1048576)       { src = x;  dst = xb;   j = i; }
    else if (i < 1835008)  { src = qw; dst = wb;   j = i - 1048576; }
    else                   { src = cw; dst = cbuf; j = i - 1835008; }
    float4 v = reinterpret_cast<const float4*>(src)[j];
    ushort4 o;
    o.x = f2bf(v.x); o.y = f2bf(v.y); o.z = f2bf(v.z); o.w = f2bf(v.w);
    reinterpret_cast<ushort4*>(dst)[j] = o;
  } else {
    const int i = (b - 8192) * 256 + threadIdx.x;
    if (i < T_SEQ) {
      int d = docs[i];
      int lo = 0, hi = i;
      while (lo < hi) { int mid = (lo + hi) >> 1; if (docs[mid] < d) lo = mid + 1; else hi = mid; }
      dstart[i] = lo;
    }
  }
}

// ---------------- bf16 GEMM: C[M][N] = A[M][K] * B[N][K]^T ----------------
// 3-buffer LDS, BK=32, counted vmcnt (never 0 in steady state), 1 barrier/K-tile,
// 2-way-max chunk swizzle, setprio around MFMA, XCD-bijective block remap.
template <int BM, int BN, int WM, int WN, typename OT>
__global__ __launch_bounds__(WM * WN * 64) void k_gemm2(const ushort* __restrict__ A,
                                                        const ushort* __restrict__ B,
                                                        OT* __restrict__ C,
                                                        int N, int K, int gx) {
  constexpr int NW  = WM * WN;
  constexpr int CHA = BM * 4;              // A 16B-chunks per K-tile
  constexpr int CHT = (BM + BN) * 4;       // total chunks per K-tile
  constexpr int LPW = CHT / (NW * 64);     // stage loads per thread per K-tile
  constexpr int TILEB = (BM + BN) * 64;    // bytes per K-tile buffer
  constexpr int MF = BM / WM / 16;
  constexpr int NF = BN / WN / 16;

  __shared__ __attribute__((aligned(16))) char lds[3 * TILEB];

  const int tid = threadIdx.x;
  const int lane = tid & 63;
  const int w = tid >> 6;
  const int lr = lane & 15, lg = lane >> 4;
  const int wm = w / WN, wn = w % WN;

  // bijective XCD remap (gridDim.x % 8 == 0 for all our shapes)
  const int nwg = gridDim.x;
  const int nb = (blockIdx.x & 7) * (nwg >> 3) + (blockIdx.x >> 3);
  const int m0 = (nb / gx) * BM;
  const int n0 = (nb % gx) * BN;

  const f4 fzero = {0.f, 0.f, 0.f, 0.f};
  f4 acc[MF][NF];
#pragma unroll
  for (int i = 0; i < MF; ++i)
#pragma unroll
    for (int j = 0; j < NF; ++j) acc[i][j] = fzero;

  const int NT = K >> 5;  // K-tiles of 32

  auto STAGE = [&](int t, int buf) {
    const int k0 = t << 5;
#pragma unroll
    for (int l = 0; l < LPW; ++l) {
      const int cb = (l * NW + w) * 64;    // wave-uniform chunk base
      const int ch = cb + lane;
      const ushort* src;
      if (ch < CHA) {
        const int row = ch >> 2;
        const int cs = (ch & 3) ^ ((row >> 1) & 3);
        src = A + (size_t)(m0 + row) * K + k0 + cs * 8;
      } else {
        const int c2 = ch - CHA;
        const int row = c2 >> 2;
        const int cs = (c2 & 3) ^ ((row >> 1) & 3);
        src = B + (size_t)(n0 + row) * K + k0 + cs * 8;
      }
      GLDS16(src, lds + buf * TILEB + cb * 16);  // wave-uniform dest + lane*16
    }
  };

  STAGE(0, 0);
  STAGE(1, 1);
  wait_vmcnt<LPW>();                 // tile 0 landed (in-order retirement)
  __builtin_amdgcn_s_barrier();

  const int sw4 = (lr >> 1) & 3;     // swizzle group (row%16 == lr for all frags)
  int bufc = 0;

  for (int t = 0; t < NT; ++t) {
    const bool more = (t + 2) < NT;
    if (more) STAGE(t + 2, bufc == 0 ? 2 : (bufc == 1 ? 0 : 1));

    const char* bb = lds + bufc * TILEB;
    sh8 af[MF], bf[NF];
#pragma unroll
    for (int mt = 0; mt < MF; ++mt) {
      const int row = wm * (BM / WM) + mt * 16 + lr;
      af[mt] = *reinterpret_cast<const sh8*>(bb + (row * 4 + (lg ^ sw4)) * 16);
    }
#pragma unroll
    for (int nt = 0; nt < NF; ++nt) {
      const int row = wn * (BN / WN) + nt * 16 + lr;
      bf[nt] = *reinterpret_cast<const sh8*>(bb + (CHA + row * 4 + (lg ^ sw4)) * 16);
    }
    __builtin_amdgcn_s_setprio(1);
#pragma unroll
    for (int mt = 0; mt < MF; ++mt)
#pragma unroll
      for (int nt = 0; nt < NF; ++nt)
        acc[mt][nt] = __builtin_amdgcn_mfma_f32_16x16x32_bf16(af[mt], bf[nt], acc[mt][nt], 0, 0, 0);
    __builtin_amdgcn_s_setprio(0);

    if (more) wait_vmcnt<LPW>();     // only t+2's loads may remain outstanding
    else      wait_vmcnt<0>();       // tail: drain so t+1 is ready
    __builtin_amdgcn_s_barrier();
    bufc = bufc == 2 ? 0 : bufc + 1;
  }

#pragma unroll
  for (int mt = 0; mt < MF; ++mt)
#pragma unroll
    for (int nt = 0; nt < NF; ++nt) {
      const int gcol = n0 + wn * (BN / WN) + nt * 16 + lr;
#pragma unroll
      for (int r = 0; r < 4; ++r) {
        const int grow = m0 + wm * (BM / WM) + mt * 16 + lg * 4 + r;
        if constexpr (sizeof(OT) == 2)
          C[(size_t)grow * N + gcol] = (OT)f2bf(acc[mt][nt][r]);
        else
          C[(size_t)grow * N + gcol] = (OT)acc[mt][nt][r];
      }
    }
}

// ---------------- fused RMSNorm + rotary + V-mix (4 (t,h) pairs / block) ----------------
__global__ __launch_bounds__(256) void k_fuse(const ushort* __restrict__ qkvb,
                                              const float* __restrict__ ve,
                                              const float* __restrict__ lam,
                                              ushort* __restrict__ qh, ushort* __restrict__ kh,
                                              ushort* __restrict__ vh) {
  const int pair = blockIdx.x * 4 + (threadIdx.x >> 6);
  const int t = pair >> 3, h = pair & 7;
  const int l = threadIdx.x & 63;
  const ushort* base = qkvb + (size_t)t * NQKV + h * HDIM + 2 * l;
  uint qu = *reinterpret_cast<const uint*>(base);
  uint ku = *reinterpret_cast<const uint*>(base + 1024);
  uint vu = *reinterpret_cast<const uint*>(base + 2048);
  float q0 = bf2f((ushort)qu), q1 = bf2f((ushort)(qu >> 16));
  float k0 = bf2f((ushort)ku), k1 = bf2f((ushort)(ku >> 16));
  float v0 = bf2f((ushort)vu), v1 = bf2f((ushort)(vu >> 16));
  float sq = q0 * q0 + q1 * q1, sk = k0 * k0 + k1 * k1;
#pragma unroll
  for (int m = 1; m < 64; m <<= 1) { sq += __shfl_xor(sq, m); sk += __shfl_xor(sk, m); }
  const float eps = 1.1920928955078125e-07f;
  float rq = rsqrtf(sq * (1.f / 128.f) + eps);
  float rk = rsqrtf(sk * (1.f / 128.f) + eps);
  q0 *= rq; q1 *= rq; k0 *= rk; k1 *= rk;
  float c0 = 1.f, s0 = 0.f, c1 = 1.f, s1 = 0.f;
  if ((l & 31) < 16) {
    const int f0 = 2 * (l & 31);
    float fr0 = exp2f(-10.f * (float)f0 * (1.f / 31.f));
    float fr1 = exp2f(-10.f * (float)(f0 + 1) * (1.f / 31.f));
    sincosf((float)t * fr0, &s0, &c0);
    sincosf((float)t * fr1, &s1, &c1);
  }
  float qx0 = __shfl_xor(q0, 32), qx1 = __shfl_xor(q1, 32);
  float kx0 = __shfl_xor(k0, 32), kx1 = __shfl_xor(k1, 32);
  const float sgn = (l < 32) ? 1.f : -1.f;
  float qr0 = q0 * c0 + sgn * qx0 * s0;
  float qr1 = q1 * c1 + sgn * qx1 * s1;
  float kr0 = k0 * c0 + sgn * kx0 * s0;
  float kr1 = k1 * c1 + sgn * kx1 * s1;
  const float l0 = lam[0], l1 = lam[1];
  float2 vev = *reinterpret_cast<const float2*>(ve + (size_t)t * DIMN + h * HDIM + 2 * l);
  float vr0 = l0 * v0 + l1 * vev.x;
  float vr1 = l0 * v1 + l1 * vev.y;
  const size_t o = ((size_t)h * T_SEQ + t) * HDIM + 2 * l;
  *reinterpret_cast<uint*>(qh + o) = (uint)f2bf(qr0) | ((uint)f2bf(qr1) << 16);
  *reinterpret_cast<uint*>(kh + o) = (uint)f2bf(kr0) | ((uint)f2bf(kr1) << 16);
  *reinterpret_cast<uint*>(vh + o) = (uint)f2bf(vr0) | ((uint)f2bf(vr1) << 16);
}

// ---------------- V transpose: vh[h][t][d] -> vt[h][d][t] ----------------
__global__ __launch_bounds__(256) void k_vt(const ushort* __restrict__ vh, ushort* __restrict__ vt) {
  const int tb = blockIdx.x, db = blockIdx.y, h = blockIdx.z;
  __shared__ ushort L[64][68];
  const int tid = threadIdx.x;
  const int t0 = tb * 64, d0 = db * 64;
  const size_t ib = ((size_t)h * T_SEQ + t0) * HDIM + d0;
#pragma unroll
  for (int p = 0; p < 4; ++p) {
    const int row = p * 16 + (tid >> 4);
    const int c4 = (tid & 15) * 4;
    ushort4 v = *reinterpret_cast<const ushort4*>(vh + ib + (size_t)row * HDIM + c4);
    *reinterpret_cast<ushort4*>(&L[row][c4]) = v;
  }
  __syncthreads();
  const size_t ob = ((size_t)h * HDIM + d0) * T_SEQ + t0;
#pragma unroll
  for (int p = 0; p < 4; ++p) {
    const int drow = p * 16 + (tid >> 4);
    const int t4 = (tid & 15) * 4;
    ushort4 v;
    v.x = L[t4 + 0][drow]; v.y = L[t4 + 1][drow];
    v.z = L[t4 + 2][drow]; v.w = L[t4 + 3][drow];
    *reinterpret_cast<ushort4*>(vt + ob + (size_t)drow * T_SEQ + t4) = v;
  }
}

// ---------------- flash attention: 4 waves, 64 q-rows, LDS-staged KV ----------------
__global__ __launch_bounds__(256) void k_attn(const ushort* __restrict__ qh,
                                              const ushort* __restrict__ kh,
                                              const ushort* __restrict__ vt,
                                              const int* __restrict__ doc_start,
                                              ushort* __restrict__ y) {
  const int h  = blockIdx.x;
  const int qb = blockIdx.y;
  const int q0 = qb * 64;
  const int tid  = threadIdx.x;
  const int wave = tid >> 6;
  const int lane = tid & 63;
  const int lr = lane & 15, lg = lane >> 4;

  __shared__ ushort Ks[2][64 * 128];
  __shared__ ushort Vs[2][128 * 64];
  __shared__ ushort Ps[4][16 * 64];

  const ushort* Kg = kh + (size_t)h * T_SEQ * HDIM;
  const ushort* Vg = vt + (size_t)h * HDIM * T_SEQ;

  const int i_me = q0 + wave * 16 + lr;
  sh8 qf[4];
  {
    const ushort* qp = qh + ((size_t)h * T_SEQ + i_me) * HDIM + lg * 8;
#pragma unroll
    for (int c = 0; c < 4; ++c) qf[c] = *reinterpret_cast<const sh8*>(qp + c * 32);
  }
  const int ds_me = doc_start[i_me];
  const int ds_hi = doc_start[q0 + 63];
  const int kb0   = doc_start[q0] >> 6;

  const f4 fzero = {0.f, 0.f, 0.f, 0.f};
  f4 o_acc[8];
#pragma unroll
  for (int i = 0; i < 8; ++i) o_acc[i] = fzero;
  float m_me = -1e30f, l_me = 0.f;

  auto STAGE = [&](int b, int k0) {
#pragma unroll
    for (int p = 0; p < 4; ++p) {
      const int c = p * 256 + tid;
      const int row = c >> 4, cc = c & 15;
      GLDS16(Kg + (size_t)(k0 + row) * HDIM + (cc ^ (row & 7)) * 8,
             &Ks[b][(p * 256 + wave * 64) * 8]);
    }
#pragma unroll
    for (int p = 0; p < 4; ++p) {
      const int c = p * 256 + tid;
      const int d = c >> 3, cc = c & 7;
      GLDS16(Vg + (size_t)d * T_SEQ + k0 + (cc ^ (d & 7)) * 8,
             &Vs[b][(p * 256 + wave * 64) * 8]);
    }
  };

  int cur = 0;
  STAGE(0, kb0 * 64);

  const int sw = (lr & 7) << 4;

  for (int kb = kb0; kb <= qb; ++kb) {
    const int k0 = kb * 64;
    __syncthreads();
    if (kb < qb) STAGE(cur ^ 1, k0 + 64);

    const char* Kb = (const char*)&Ks[cur][0];
    const char* Vb = (const char*)&Vs[cur][0];
    char* Pw = (char*)&Ps[wave][0];

    f4 sacc[4];
#pragma unroll
    for (int jt = 0; jt < 4; ++jt) sacc[jt] = fzero;
#pragma unroll
    for (int jt = 0; jt < 4; ++jt)
#pragma unroll
      for (int c = 0; c < 4; ++c) {
        sh8 kf = *reinterpret_cast<const sh8*>(Kb + (jt * 16 + lr) * 256 + ((c * 64 + lg * 16) ^ sw));
        sacc[jt] = __builtin_amdgcn_mfma_f32_16x16x32_bf16(kf, qf[c], sacc[jt], 0, 0, 0);
      }

    const bool fullblk = (kb < qb) && (ds_hi <= k0);
    float p[4][4];
#pragma unroll
    for (int jt = 0; jt < 4; ++jt)
#pragma unroll
      for (int r = 0; r < 4; ++r) {
        float s = sacc[jt][r] * ATTN_SCALE;
        const int j = k0 + jt * 16 + lg * 4 + r;
        bool valid = fullblk || ((j <= i_me) && (j >= ds_me));
        p[jt][r] = valid ? s : -1e30f;
      }
    float tm = -1e30f;
#pragma unroll
    for (int jt = 0; jt < 4; ++jt) {
      float a = fmaxf(p[jt][0], p[jt][1]), b = fmaxf(p[jt][2], p[jt][3]);
      tm = fmaxf(tm, fmaxf(a, b));
    }
    tm = fmaxf(tm, __shfl_xor(tm, 16));
    tm = fmaxf(tm, __shfl_xor(tm, 32));
    const float mnew = fmaxf(m_me, tm);
    const float sc = __expf(m_me - mnew);
    m_me = mnew;
    float rs = 0.f;
#pragma unroll
    for (int jt = 0; jt < 4; ++jt)
#pragma unroll
      for (int r = 0; r < 4; ++r) {
        float pv = __expf(p[jt][r] - mnew);
        p[jt][r] = pv;
        rs += pv;
      }
    rs += __shfl_xor(rs, 16);
    rs += __shfl_xor(rs, 32);
    l_me = l_me * sc + rs;

#pragma unroll
    for (int jt = 0; jt < 4; ++jt) {
      uint2 u;
      u.x = (uint)f2bf(p[jt][0]) | ((uint)f2bf(p[jt][1]) << 16);
      u.y = (uint)f2bf(p[jt][2]) | ((uint)f2bf(p[jt][3]) << 16);
      *reinterpret_cast<uint2*>(Pw + lr * 128 + ((jt * 32 + lg * 8) ^ sw)) = u;
    }

    float sco[4];
#pragma unroll
    for (int rr = 0; rr < 4; ++rr) sco[rr] = __shfl(sc, lg * 4 + rr);
#pragma unroll
    for (int dt = 0; dt < 8; ++dt)
#pragma unroll
      for (int rr = 0; rr < 4; ++rr) o_acc[dt][rr] *= sco[rr];

#pragma unroll
    for (int ks = 0; ks < 2; ++ks) {
      sh8 pa = *reinterpret_cast<const sh8*>(Pw + lr * 128 + ((ks * 64 + lg * 16) ^ sw));
#pragma unroll
      for (int dt = 0; dt < 8; ++dt) {
        sh8 vf = *reinterpret_cast<const sh8*>(Vb + (dt * 16 + lr) * 128 + ((ks * 64 + lg * 16) ^ sw));
        o_acc[dt] = __builtin_amdgcn_mfma_f32_16x16x32_bf16(pa, vf, o_acc[dt], 0, 0, 0);
      }
    }

    __builtin_amdgcn_s_barrier();
    cur ^= 1;
  }

  float lo[4];
#pragma unroll
  for (int rr = 0; rr < 4; ++rr) lo[rr] = __shfl(l_me, lg * 4 + rr);
#pragma unroll
  for (int dt = 0; dt < 8; ++dt)
#pragma unroll
    for (int rr = 0; rr < 4; ++rr) {
      const int trow = q0 + wave * 16 + lg * 4 + rr;
      y[(size_t)trow * DIMN + h * HDIM + dt * 16 + lr] = f2bf(o_acc[dt][rr] / lo[rr]);
    }
}

extern "C" void kernel_launch(void* const* d_in, const int* in_sizes, int n_in,
                              void* d_out, int out_size, void* d_ws, size_t ws_size,
                              hipStream_t stream) {
  const float* x    = (const float*)d_in[0];
  const float* ve   = (const float*)d_in[1];
  const float* qkvw = (const float*)d_in[2];
  const float* lam  = (const float*)d_in[3];
  const float* cpw  = (const float*)d_in[4];
  const int*   docs = (const int*)d_in[5];
  float* out = (float*)d_out;
  char* ws = (char*)d_ws;

  ushort* qkvb = (ushort*)(ws);                    // 24MB  [0,24)
  ushort* xb   = (ushort*)(ws + (24ull << 20));    // 8MB   [24,32)
  ushort* wb   = (ushort*)(ws + (32ull << 20));    // 6MB   [32,38)
  ushort* cb   = (ushort*)(ws + (38ull << 20));    // 2MB   [38,40)
  ushort* qh   = (ushort*)(ws + (40ull << 20));    // 8MB   [40,48)
  ushort* kh   = (ushort*)(ws + (48ull << 20));    // 8MB   [48,56)
  ushort* vh   = (ushort*)(ws + (56ull << 20));    // 8MB   [56,64)
  ushort* vt   = (ushort*)(ws + (64ull << 20));    // 8MB   [64,72)
  ushort* yb   = (ushort*)(ws + (72ull << 20));    // 8MB   [72,80)
  int*  dstart = (int*)(ws + (80ull << 20));       // 16KB

  k_prep<<<8192 + 16, 256, 0, stream>>>(x, qkvw, cpw, xb, wb, cb, docs, dstart);

  // QKV: M=4096, N=3072, K=1024 — 256x128 tile, grid 16x24=384 (%8==0)
  k_gemm2<256, 128, 2, 2, ushort><<<384, 256, 0, stream>>>(xb, wb, qkvb, NQKV, DIMN, NQKV / 128);

  k_fuse<<<T_SEQ * NH / 4, 256, 0, stream>>>(qkvb, ve, lam, qh, kh, vh);
  k_vt<<<dim3(T_SEQ / 64, HDIM / 64, NH), 256, 0, stream>>>(vh, vt);

  k_attn<<<dim3(NH, T_SEQ / 64), 256, 0, stream>>>(qh, kh, vt, dstart, yb);

  // proj: M=4096, N=1024, K=1024 — 128x128 tile, grid 32x8=256 (%8==0)
  k_gemm2<128, 128, 2, 2, float><<<256, 256, 0, stream>>>(yb, cb, out, DIMN, DIMN, DIMN / 128);
}

// Round 5
// 106.899 us; speedup vs baseline: 1.6056x; 1.1012x over previous
//
#include <hip/hip_runtime.h>
#include <hip/hip_bf16.h>
#include <cstdint>

typedef __attribute__((ext_vector_type(8))) short sh8;   // 8 x bf16 bits
typedef __attribute__((ext_vector_type(4))) float f4;    // MFMA accumulator

#define T_SEQ 4096
#define DIMN  1024
#define NH    8
#define HDIM  128
#define NQKV  3072
#define ATTN_SCALE 0.12f

__device__ __forceinline__ ushort f2bf(float x) {
  __hip_bfloat16 b = __float2bfloat16(x);
  return *reinterpret_cast<ushort*>(&b);
}
__device__ __forceinline__ float bf2f(ushort u) {
  uint v = ((uint)u) << 16;
  float f;
  __builtin_memcpy(&f, &v, 4);
  return f;
}

#define GLDS16(g, l) \
  __builtin_amdgcn_global_load_lds((const __attribute__((address_space(1))) void*)(g), \
                                   (__attribute__((address_space(3))) void*)(l), 16, 0, 0)

template <int N>
__device__ __forceinline__ void wait_vmcnt() {
  if constexpr (N == 0)      asm volatile("s_waitcnt vmcnt(0)" ::: "memory");
  else if constexpr (N == 4) asm volatile("s_waitcnt vmcnt(4)" ::: "memory");
  else if constexpr (N == 6) asm volatile("s_waitcnt vmcnt(6)" ::: "memory");
  else if constexpr (N == 8) asm volatile("s_waitcnt vmcnt(8)" ::: "memory");
  __builtin_amdgcn_sched_barrier(0);
}
#define LGKM0 do { asm volatile("s_waitcnt lgkmcnt(0)" ::: "memory"); __builtin_amdgcn_sched_barrier(0); } while (0)
#define BAR   __builtin_amdgcn_s_barrier()

// ---------------- prep: 3 fp32->bf16 converts + doc_start ----------------
__global__ __launch_bounds__(256) void k_prep(const float* __restrict__ x,
                                              const float* __restrict__ qw,
                                              const float* __restrict__ cw,
                                              ushort* __restrict__ xb, ushort* __restrict__ wb,
                                              ushort* __restrict__ cbuf,
                                              const int* __restrict__ docs, int* __restrict__ dstart) {
  const int b = blockIdx.x;
  if (b < 8192) {
    const int i = b * 256 + threadIdx.x;  // float4 index over concatenated buffers
    const float* src;
    ushort* dst;
    int j;
    if (i < 1048576)       { src = x;  dst = xb;   j = i; }
    else if (i < 1835008)  { src = qw; dst = wb;   j = i - 1048576; }
    else                   { src = cw; dst = cbuf; j = i - 1835008; }
    float4 v = reinterpret_cast<const float4*>(src)[j];
    ushort4 o;
    o.x = f2bf(v.x); o.y = f2bf(v.y); o.z = f2bf(v.z); o.w = f2bf(v.w);
    reinterpret_cast<ushort4*>(dst)[j] = o;
  } else {
    const int i = (b - 8192) * 256 + threadIdx.x;
    if (i < T_SEQ) {
      int d = docs[i];
      int lo = 0, hi = i;
      while (lo < hi) { int mid = (lo + hi) >> 1; if (docs[mid] < d) lo = mid + 1; else hi = mid; }
      dstart[i] = lo;
    }
  }
}

// ---------------- 8-phase 256x256 GEMM (m201 port): C = A[M][K] * B[N][K]^T ----------------
// 8 waves (2M x 4N), BK=64, 2 LDS tile-buffers x 4 halves (A0,A1,B0,B1 of 128x64),
// counted vmcnt(6) at phases 4/8 only, setprio around MFMA clusters, XOR-swizzled LDS.
#define RD_A(buf, mh) do {                                                         \
  const char* hb_ = (const char*)&lds[buf][wave_m][0];                             \
  _Pragma("unroll") for (int mt = 0; mt < 4; ++mt) {                               \
    const int row_ = (mh) * 64 + mt * 16 + lr;                                     \
    _Pragma("unroll") for (int kk = 0; kk < 2; ++kk)                               \
      a_cur[mt][kk] = *reinterpret_cast<const sh8*>(                               \
          hb_ + row_ * 128 + ((((kk << 2) | lg) ^ (lr & 7)) << 4));                \
  }                                                                                \
} while (0)

#define RD_B(buf, nh, dst) do {                                                    \
  const char* hb_ = (const char*)&lds[buf][2 + (wave_n >> 1)][0];                  \
  _Pragma("unroll") for (int nt = 0; nt < 2; ++nt) {                               \
    const int row_ = (wave_n & 1) * 64 + (nh) * 32 + nt * 16 + lr;                 \
    _Pragma("unroll") for (int kk = 0; kk < 2; ++kk)                               \
      dst[nt][kk] = *reinterpret_cast<const sh8*>(                                 \
          hb_ + row_ * 128 + ((((kk << 2) | lg) ^ (lr & 7)) << 4));                \
  }                                                                                \
} while (0)

#define MFMA16(mh, nh, bb) do {                                                    \
  __builtin_amdgcn_s_setprio(1);                                                   \
  _Pragma("unroll") for (int mt = 0; mt < 4; ++mt)                                 \
  _Pragma("unroll") for (int nt = 0; nt < 2; ++nt)                                 \
  _Pragma("unroll") for (int kk = 0; kk < 2; ++kk)                                 \
    acc[(mh) * 4 + mt][(nh) * 2 + nt] = __builtin_amdgcn_mfma_f32_16x16x32_bf16(   \
        a_cur[mt][kk], bb[nt][kk], acc[(mh) * 4 + mt][(nh) * 2 + nt], 0, 0, 0);    \
  __builtin_amdgcn_s_setprio(0);                                                   \
} while (0)

__global__ __launch_bounds__(512, 2) void k_gemm8(const ushort* __restrict__ A,
                                                  const ushort* __restrict__ B,
                                                  ushort* __restrict__ C,
                                                  int N, int K, int gx) {
  __shared__ ushort lds[2][4][128 * 64];   // [buf][A0,A1,B0,B1][row*64+col] = 128KB
  const int tid = threadIdx.x;
  const int lane = tid & 63;
  const int w = tid >> 6;
  const int lr = lane & 15, lg = lane >> 4;
  const int wave_m = w >> 2, wave_n = w & 3;

  const int nwg = gridDim.x;
  const int nb = (blockIdx.x & 7) * (nwg >> 3) + (blockIdx.x >> 3);  // nwg%8==0
  const int m0 = (nb / gx) * 256;
  const int n0 = (nb % gx) * 256;

  f4 acc[8][4];
  const f4 fzero = {0.f, 0.f, 0.f, 0.f};
#pragma unroll
  for (int i = 0; i < 8; ++i)
#pragma unroll
    for (int j = 0; j < 4; ++j) acc[i][j] = fzero;

  // stage one 128x64 half (16KB): 2 x global_load_lds(16B) per thread
  auto stage_half = [&](int buf, int half, const ushort* base, int rowb, int k0) {
#pragma unroll
    for (int l = 0; l < 2; ++l) {
      const int chunk = l * 512 + tid;           // 0..1023
      const int row = chunk >> 3, cj = chunk & 7;
      GLDS16(base + (size_t)(rowb + row) * K + k0 + ((cj ^ (row & 7)) << 3),
             &lds[buf][half][(l * 512 + w * 64) * 8]);
    }
  };

  sh8 a_cur[4][2], b0[2][2], b1[2][2];

  const int NT = K >> 6;        // K-tiles of 64 (even)
  const int NP = NT >> 1;       // periods of 2 tiles

  // prologue: tile0 full (buf0) + tile1 minus A-h1 (buf1)
  stage_half(0, 2, B, n0, 0);       stage_half(0, 3, B, n0 + 128, 0);
  stage_half(0, 0, A, m0, 0);       stage_half(0, 1, A, m0 + 128, 0);
  stage_half(1, 2, B, n0, 64);      stage_half(1, 3, B, n0 + 128, 64);
  stage_half(1, 0, A, m0, 64);
  wait_vmcnt<6>();                  // tile0's 4 halves landed
  BAR;

  for (int p = 0; p < NP; ++p) {
    const int kO  = (p * 2 + 1) << 6;   // odd tile k0
    const int kN0 = (p * 2 + 2) << 6;   // next even tile
    const int kN1 = (p * 2 + 3) << 6;   // next odd tile
    const bool more = (p + 1) < NP;

    // P1: (m0,n0) on buf0; stage A-h1 of odd tile -> buf1
    RD_A(0, 0); RD_B(0, 0, b0);
    stage_half(1, 1, A, m0 + 128, kO);
    BAR; LGKM0; MFMA16(0, 0, b0); BAR;
    // P2: (m0,n1)
    RD_B(0, 1, b1);
    BAR; LGKM0; MFMA16(0, 1, b1); BAR;
    // P3: (m1,n0); stage B halves of next even tile -> buf0
    RD_A(0, 1);
    if (more) { stage_half(0, 2, B, n0, kN0); stage_half(0, 3, B, n0 + 128, kN0); }
    BAR; LGKM0; MFMA16(1, 0, b0); BAR;
    // P4: (m1,n1); stage A-h0 next even -> buf0; W4
    if (more) { stage_half(0, 0, A, m0, kN0); wait_vmcnt<6>(); }
    else      { wait_vmcnt<0>(); }
    BAR; MFMA16(1, 1, b1); BAR;
    // P5: (m0,n0) on buf1; stage A-h1 next even -> buf0
    RD_A(1, 0); RD_B(1, 0, b0);
    if (more) stage_half(0, 1, A, m0 + 128, kN0);
    BAR; LGKM0; MFMA16(0, 0, b0); BAR;
    // P6: (m0,n1)
    RD_B(1, 1, b1);
    BAR; LGKM0; MFMA16(0, 1, b1); BAR;
    // P7: (m1,n0); stage B halves of next odd tile -> buf1
    RD_A(1, 1);
    if (more) { stage_half(1, 2, B, n0, kN1); stage_half(1, 3, B, n0 + 128, kN1); }
    BAR; LGKM0; MFMA16(1, 0, b0); BAR;
    // P8: (m1,n1); stage A-h0 next odd -> buf1; W8
    if (more) stage_half(1, 0, A, m0, kN1);
    wait_vmcnt<6>();
    BAR; MFMA16(1, 1, b1); BAR;
  }

#pragma unroll
  for (int mf = 0; mf < 8; ++mf)
#pragma unroll
    for (int nf = 0; nf < 4; ++nf) {
      const int gcol = n0 + wave_n * 64 + nf * 16 + lr;
#pragma unroll
      for (int r = 0; r < 4; ++r) {
        const int grow = m0 + wave_m * 128 + mf * 16 + lg * 4 + r;
        C[(size_t)grow * N + gcol] = f2bf(acc[mf][nf][r]);
      }
    }
}

// ---------------- proj GEMM: 3-buffer BK=32 (R4 structure), 128x128 ----------------
template <int BM, int BN, int WM, int WN, typename OT>
__global__ __launch_bounds__(WM * WN * 64) void k_gemm2(const ushort* __restrict__ A,
                                                        const ushort* __restrict__ B,
                                                        OT* __restrict__ C,
                                                        int N, int K, int gx) {
  constexpr int NW  = WM * WN;
  constexpr int CHA = BM * 4;
  constexpr int CHT = (BM + BN) * 4;
  constexpr int LPW = CHT / (NW * 64);
  constexpr int TILEB = (BM + BN) * 64;
  constexpr int MF = BM / WM / 16;
  constexpr int NF = BN / WN / 16;

  __shared__ __attribute__((aligned(16))) char lds[3 * TILEB];

  const int tid = threadIdx.x;
  const int lane = tid & 63;
  const int w = tid >> 6;
  const int lr = lane & 15, lg = lane >> 4;
  const int wm = w / WN, wn = w % WN;

  const int nwg = gridDim.x;
  const int nb = (blockIdx.x & 7) * (nwg >> 3) + (blockIdx.x >> 3);
  const int m0 = (nb / gx) * BM;
  const int n0 = (nb % gx) * BN;

  const f4 fzero = {0.f, 0.f, 0.f, 0.f};
  f4 acc[MF][NF];
#pragma unroll
  for (int i = 0; i < MF; ++i)
#pragma unroll
    for (int j = 0; j < NF; ++j) acc[i][j] = fzero;

  const int NT = K >> 5;

  auto STAGE = [&](int t, int buf) {
    const int k0 = t << 5;
#pragma unroll
    for (int l = 0; l < LPW; ++l) {
      const int cb = (l * NW + w) * 64;
      const int ch = cb + lane;
      const ushort* src;
      if (ch < CHA) {
        const int row = ch >> 2;
        const int cs = (ch & 3) ^ ((row >> 1) & 3);
        src = A + (size_t)(m0 + row) * K + k0 + cs * 8;
      } else {
        const int c2 = ch - CHA;
        const int row = c2 >> 2;
        const int cs = (c2 & 3) ^ ((row >> 1) & 3);
        src = B + (size_t)(n0 + row) * K + k0 + cs * 8;
      }
      GLDS16(src, lds + buf * TILEB + cb * 16);
    }
  };

  STAGE(0, 0);
  STAGE(1, 1);
  wait_vmcnt<LPW>();
  __builtin_amdgcn_s_barrier();

  const int sw4 = (lr >> 1) & 3;
  int bufc = 0;

  for (int t = 0; t < NT; ++t) {
    const bool more = (t + 2) < NT;
    if (more) STAGE(t + 2, bufc == 0 ? 2 : (bufc == 1 ? 0 : 1));

    const char* bb = lds + bufc * TILEB;
    sh8 af[MF], bf[NF];
#pragma unroll
    for (int mt = 0; mt < MF; ++mt) {
      const int row = wm * (BM / WM) + mt * 16 + lr;
      af[mt] = *reinterpret_cast<const sh8*>(bb + (row * 4 + (lg ^ sw4)) * 16);
    }
#pragma unroll
    for (int nt = 0; nt < NF; ++nt) {
      const int row = wn * (BN / WN) + nt * 16 + lr;
      bf[nt] = *reinterpret_cast<const sh8*>(bb + (CHA + row * 4 + (lg ^ sw4)) * 16);
    }
    __builtin_amdgcn_s_setprio(1);
#pragma unroll
    for (int mt = 0; mt < MF; ++mt)
#pragma unroll
      for (int nt = 0; nt < NF; ++nt)
        acc[mt][nt] = __builtin_amdgcn_mfma_f32_16x16x32_bf16(af[mt], bf[nt], acc[mt][nt], 0, 0, 0);
    __builtin_amdgcn_s_setprio(0);

    if (more) wait_vmcnt<LPW>();
    else      wait_vmcnt<0>();
    __builtin_amdgcn_s_barrier();
    bufc = bufc == 2 ? 0 : bufc + 1;
  }

#pragma unroll
  for (int mt = 0; mt < MF; ++mt)
#pragma unroll
    for (int nt = 0; nt < NF; ++nt) {
      const int gcol = n0 + wn * (BN / WN) + nt * 16 + lr;
#pragma unroll
      for (int r = 0; r < 4; ++r) {
        const int grow = m0 + wm * (BM / WM) + mt * 16 + lg * 4 + r;
        if constexpr (sizeof(OT) == 2)
          C[(size_t)grow * N + gcol] = (OT)f2bf(acc[mt][nt][r]);
        else
          C[(size_t)grow * N + gcol] = (OT)acc[mt][nt][r];
      }
    }
}

// ---------------- fused RMSNorm + rotary + V-mix (4 (t,h) pairs / block) ----------------
__global__ __launch_bounds__(256) void k_fuse(const ushort* __restrict__ qkvb,
                                              const float* __restrict__ ve,
                                              const float* __restrict__ lam,
                                              ushort* __restrict__ qh, ushort* __restrict__ kh,
                                              ushort* __restrict__ vh) {
  const int pair = blockIdx.x * 4 + (threadIdx.x >> 6);
  const int t = pair >> 3, h = pair & 7;
  const int l = threadIdx.x & 63;
  const ushort* base = qkvb + (size_t)t * NQKV + h * HDIM + 2 * l;
  uint qu = *reinterpret_cast<const uint*>(base);
  uint ku = *reinterpret_cast<const uint*>(base + 1024);
  uint vu = *reinterpret_cast<const uint*>(base + 2048);
  float q0 = bf2f((ushort)qu), q1 = bf2f((ushort)(qu >> 16));
  float k0 = bf2f((ushort)ku), k1 = bf2f((ushort)(ku >> 16));
  float v0 = bf2f((ushort)vu), v1 = bf2f((ushort)(vu >> 16));
  float sq = q0 * q0 + q1 * q1, sk = k0 * k0 + k1 * k1;
#pragma unroll
  for (int m = 1; m < 64; m <<= 1) { sq += __shfl_xor(sq, m); sk += __shfl_xor(sk, m); }
  const float eps = 1.1920928955078125e-07f;
  float rq = rsqrtf(sq * (1.f / 128.f) + eps);
  float rk = rsqrtf(sk * (1.f / 128.f) + eps);
  q0 *= rq; q1 *= rq; k0 *= rk; k1 *= rk;
  float c0 = 1.f, s0 = 0.f, c1 = 1.f, s1 = 0.f;
  if ((l & 31) < 16) {
    const int f0 = 2 * (l & 31);
    float fr0 = exp2f(-10.f * (float)f0 * (1.f / 31.f));
    float fr1 = exp2f(-10.f * (float)(f0 + 1) * (1.f / 31.f));
    sincosf((float)t * fr0, &s0, &c0);
    sincosf((float)t * fr1, &s1, &c1);
  }
  float qx0 = __shfl_xor(q0, 32), qx1 = __shfl_xor(q1, 32);
  float kx0 = __shfl_xor(k0, 32), kx1 = __shfl_xor(k1, 32);
  const float sgn = (l < 32) ? 1.f : -1.f;
  float qr0 = q0 * c0 + sgn * qx0 * s0;
  float qr1 = q1 * c1 + sgn * qx1 * s1;
  float kr0 = k0 * c0 + sgn * kx0 * s0;
  float kr1 = k1 * c1 + sgn * kx1 * s1;
  const float l0 = lam[0], l1 = lam[1];
  float2 vev = *reinterpret_cast<const float2*>(ve + (size_t)t * DIMN + h * HDIM + 2 * l);
  float vr0 = l0 * v0 + l1 * vev.x;
  float vr1 = l0 * v1 + l1 * vev.y;
  const size_t o = ((size_t)h * T_SEQ + t) * HDIM + 2 * l;
  *reinterpret_cast<uint*>(qh + o) = (uint)f2bf(qr0) | ((uint)f2bf(qr1) << 16);
  *reinterpret_cast<uint*>(kh + o) = (uint)f2bf(kr0) | ((uint)f2bf(kr1) << 16);
  *reinterpret_cast<uint*>(vh + o) = (uint)f2bf(vr0) | ((uint)f2bf(vr1) << 16);
}

// ---------------- V transpose: vh[h][t][d] -> vt[h][d][t] ----------------
__global__ __launch_bounds__(256) void k_vt(const ushort* __restrict__ vh, ushort* __restrict__ vt) {
  const int tb = blockIdx.x, db = blockIdx.y, h = blockIdx.z;
  __shared__ ushort L[64][68];
  const int tid = threadIdx.x;
  const int t0 = tb * 64, d0 = db * 64;
  const size_t ib = ((size_t)h * T_SEQ + t0) * HDIM + d0;
#pragma unroll
  for (int p = 0; p < 4; ++p) {
    const int row = p * 16 + (tid >> 4);
    const int c4 = (tid & 15) * 4;
    ushort4 v = *reinterpret_cast<const ushort4*>(vh + ib + (size_t)row * HDIM + c4);
    *reinterpret_cast<ushort4*>(&L[row][c4]) = v;
  }
  __syncthreads();
  const size_t ob = ((size_t)h * HDIM + d0) * T_SEQ + t0;
#pragma unroll
  for (int p = 0; p < 4; ++p) {
    const int drow = p * 16 + (tid >> 4);
    const int t4 = (tid & 15) * 4;
    ushort4 v;
    v.x = L[t4 + 0][drow]; v.y = L[t4 + 1][drow];
    v.z = L[t4 + 2][drow]; v.w = L[t4 + 3][drow];
    *reinterpret_cast<ushort4*>(vt + ob + (size_t)drow * T_SEQ + t4) = v;
  }
}

// ---------------- flash attention: 4 waves, 64 q-rows, LDS-staged KV ----------------
__global__ __launch_bounds__(256) void k_attn(const ushort* __restrict__ qh,
                                              const ushort* __restrict__ kh,
                                              const ushort* __restrict__ vt,
                                              const int* __restrict__ doc_start,
                                              ushort* __restrict__ y) {
  const int h  = blockIdx.x;
  const int qb = blockIdx.y;
  const int q0 = qb * 64;
  const int tid  = threadIdx.x;
  const int wave = tid >> 6;
  const int lane = tid & 63;
  const int lr = lane & 15, lg = lane >> 4;

  __shared__ ushort Ks[2][64 * 128];
  __shared__ ushort Vs[2][128 * 64];
  __shared__ ushort Ps[4][16 * 64];

  const ushort* Kg = kh + (size_t)h * T_SEQ * HDIM;
  const ushort* Vg = vt + (size_t)h * HDIM * T_SEQ;

  const int i_me = q0 + wave * 16 + lr;
  sh8 qf[4];
  {
    const ushort* qp = qh + ((size_t)h * T_SEQ + i_me) * HDIM + lg * 8;
#pragma unroll
    for (int c = 0; c < 4; ++c) qf[c] = *reinterpret_cast<const sh8*>(qp + c * 32);
  }
  const int ds_me = doc_start[i_me];
  const int ds_hi = doc_start[q0 + 63];
  const int kb0   = doc_start[q0] >> 6;

  const f4 fzero = {0.f, 0.f, 0.f, 0.f};
  f4 o_acc[8];
#pragma unroll
  for (int i = 0; i < 8; ++i) o_acc[i] = fzero;
  float m_me = -1e30f, l_me = 0.f;

  auto STAGE = [&](int b, int k0) {
#pragma unroll
    for (int p = 0; p < 4; ++p) {
      const int c = p * 256 + tid;
      const int row = c >> 4, cc = c & 15;
      GLDS16(Kg + (size_t)(k0 + row) * HDIM + (cc ^ (row & 7)) * 8,
             &Ks[b][(p * 256 + wave * 64) * 8]);
    }
#pragma unroll
    for (int p = 0; p < 4; ++p) {
      const int c = p * 256 + tid;
      const int d = c >> 3, cc = c & 7;
      GLDS16(Vg + (size_t)d * T_SEQ + k0 + (cc ^ (d & 7)) * 8,
             &Vs[b][(p * 256 + wave * 64) * 8]);
    }
  };

  int cur = 0;
  STAGE(0, kb0 * 64);

  const int sw = (lr & 7) << 4;

  for (int kb = kb0; kb <= qb; ++kb) {
    const int k0 = kb * 64;
    __syncthreads();
    if (kb < qb) STAGE(cur ^ 1, k0 + 64);

    const char* Kb = (const char*)&Ks[cur][0];
    const char* Vb = (const char*)&Vs[cur][0];
    char* Pw = (char*)&Ps[wave][0];

    f4 sacc[4];
#pragma unroll
    for (int jt = 0; jt < 4; ++jt) sacc[jt] = fzero;
#pragma unroll
    for (int jt = 0; jt < 4; ++jt)
#pragma unroll
      for (int c = 0; c < 4; ++c) {
        sh8 kf = *reinterpret_cast<const sh8*>(Kb + (jt * 16 + lr) * 256 + ((c * 64 + lg * 16) ^ sw));
        sacc[jt] = __builtin_amdgcn_mfma_f32_16x16x32_bf16(kf, qf[c], sacc[jt], 0, 0, 0);
      }

    const bool fullblk = (kb < qb) && (ds_hi <= k0);
    float p[4][4];
#pragma unroll
    for (int jt = 0; jt < 4; ++jt)
#pragma unroll
      for (int r = 0; r < 4; ++r) {
        float s = sacc[jt][r] * ATTN_SCALE;
        const int j = k0 + jt * 16 + lg * 4 + r;
        bool valid = fullblk || ((j <= i_me) && (j >= ds_me));
        p[jt][r] = valid ? s : -1e30f;
      }
    float tm = -1e30f;
#pragma unroll
    for (int jt = 0; jt < 4; ++jt) {
      float a = fmaxf(p[jt][0], p[jt][1]), b = fmaxf(p[jt][2], p[jt][3]);
      tm = fmaxf(tm, fmaxf(a, b));
    }
    tm = fmaxf(tm, __shfl_xor(tm, 16));
    tm = fmaxf(tm, __shfl_xor(tm, 32));
    const float mnew = fmaxf(m_me, tm);
    const float sc = __expf(m_me - mnew);
    m_me = mnew;
    float rs = 0.f;
#pragma unroll
    for (int jt = 0; jt < 4; ++jt)
#pragma unroll
      for (int r = 0; r < 4; ++r) {
        float pv = __expf(p[jt][r] - mnew);
        p[jt][r] = pv;
        rs += pv;
      }
    rs += __shfl_xor(rs, 16);
    rs += __shfl_xor(rs, 32);
    l_me = l_me * sc + rs;

#pragma unroll
    for (int jt = 0; jt < 4; ++jt) {
      uint2 u;
      u.x = (uint)f2bf(p[jt][0]) | ((uint)f2bf(p[jt][1]) << 16);
      u.y = (uint)f2bf(p[jt][2]) | ((uint)f2bf(p[jt][3]) << 16);
      *reinterpret_cast<uint2*>(Pw + lr * 128 + ((jt * 32 + lg * 8) ^ sw)) = u;
    }

    float sco[4];
#pragma unroll
    for (int rr = 0; rr < 4; ++rr) sco[rr] = __shfl(sc, lg * 4 + rr);
#pragma unroll
    for (int dt = 0; dt < 8; ++dt)
#pragma unroll
      for (int rr = 0; rr < 4; ++rr) o_acc[dt][rr] *= sco[rr];

#pragma unroll
    for (int ks = 0; ks < 2; ++ks) {
      sh8 pa = *reinterpret_cast<const sh8*>(Pw + lr * 128 + ((ks * 64 + lg * 16) ^ sw));
#pragma unroll
      for (int dt = 0; dt < 8; ++dt) {
        sh8 vf = *reinterpret_cast<const sh8*>(Vb + (dt * 16 + lr) * 128 + ((ks * 64 + lg * 16) ^ sw));
        o_acc[dt] = __builtin_amdgcn_mfma_f32_16x16x32_bf16(pa, vf, o_acc[dt], 0, 0, 0);
      }
    }

    __builtin_amdgcn_s_barrier();
    cur ^= 1;
  }

  float lo[4];
#pragma unroll
  for (int rr = 0; rr < 4; ++rr) lo[rr] = __shfl(l_me, lg * 4 + rr);
#pragma unroll
  for (int dt = 0; dt < 8; ++dt)
#pragma unroll
    for (int rr = 0; rr < 4; ++rr) {
      const int trow = q0 + wave * 16 + lg * 4 + rr;
      y[(size_t)trow * DIMN + h * HDIM + dt * 16 + lr] = f2bf(o_acc[dt][rr] / lo[rr]);
    }
}

extern "C" void kernel_launch(void* const* d_in, const int* in_sizes, int n_in,
                              void* d_out, int out_size, void* d_ws, size_t ws_size,
                              hipStream_t stream) {
  const float* x    = (const float*)d_in[0];
  const float* ve   = (const float*)d_in[1];
  const float* qkvw = (const float*)d_in[2];
  const float* lam  = (const float*)d_in[3];
  const float* cpw  = (const float*)d_in[4];
  const int*   docs = (const int*)d_in[5];
  float* out = (float*)d_out;
  char* ws = (char*)d_ws;

  ushort* qkvb = (ushort*)(ws);                    // 24MB  [0,24)
  ushort* xb   = (ushort*)(ws + (24ull << 20));    // 8MB   [24,32)
  ushort* wb   = (ushort*)(ws + (32ull << 20));    // 6MB   [32,38)
  ushort* cb   = (ushort*)(ws + (38ull << 20));    // 2MB   [38,40)
  ushort* qh   = (ushort*)(ws + (40ull << 20));    // 8MB   [40,48)
  ushort* kh   = (ushort*)(ws + (48ull << 20));    // 8MB   [48,56)
  ushort* vh   = (ushort*)(ws + (56ull << 20));    // 8MB   [56,64)
  ushort* vt   = (ushort*)(ws + (64ull << 20));    // 8MB   [64,72)
  ushort* yb   = (ushort*)(ws + (72ull << 20));    // 8MB   [72,80)
  int*  dstart = (int*)(ws + (80ull << 20));       // 16KB

  k_prep<<<8192 + 16, 256, 0, stream>>>(x, qkvw, cpw, xb, wb, cb, docs, dstart);

  // QKV: M=4096, N=3072, K=1024 — 8-phase 256x256, grid 16x12=192 (%8==0)
  k_gemm8<<<192, 512, 0, stream>>>(xb, wb, qkvb, NQKV, DIMN, NQKV / 256);

  k_fuse<<<T_SEQ * NH / 4, 256, 0, stream>>>(qkvb, ve, lam, qh, kh, vh);
  k_vt<<<dim3(T_SEQ / 64, HDIM / 64, NH), 256, 0, stream>>>(vh, vt);

  k_attn<<<dim3(NH, T_SEQ / 64), 256, 0, stream>>>(qh, kh, vt, dstart, yb);

  // proj: M=4096, N=1024, K=1024 — 128x128 tile, grid 32x8=256 (%8==0)
  k_gemm2<128, 128, 2, 2, float><<<256, 256, 0, stream>>>(yb, cb, out, DIMN, DIMN, DIMN / 128);
}

// Round 6
// 102.481 us; speedup vs baseline: 1.6749x; 1.0431x over previous
//
#include <hip/hip_runtime.h>
#include <hip/hip_bf16.h>
#include <cstdint>

typedef __attribute__((ext_vector_type(8))) short sh8;    // 8 x bf16 bits
typedef __attribute__((ext_vector_type(4))) float f4;     // 16x16 MFMA acc
typedef __attribute__((ext_vector_type(16))) float f16v;  // 32x32 MFMA acc

#define T_SEQ 4096
#define DIMN  1024
#define NH    8
#define HDIM  128
#define NQKV  3072
#define ATTN_SCALE 0.12f

__device__ __forceinline__ ushort f2bf(float x) {
  __hip_bfloat16 b = __float2bfloat16(x);
  return *reinterpret_cast<ushort*>(&b);
}
__device__ __forceinline__ float bf2f(ushort u) {
  uint v = ((uint)u) << 16;
  float f;
  __builtin_memcpy(&f, &v, 4);
  return f;
}

#define GLDS16(g, l) \
  __builtin_amdgcn_global_load_lds((const __attribute__((address_space(1))) void*)(g), \
                                   (__attribute__((address_space(3))) void*)(l), 16, 0, 0)

template <int N>
__device__ __forceinline__ void wait_vmcnt() {
  if constexpr (N == 0)      asm volatile("s_waitcnt vmcnt(0)" ::: "memory");
  else if constexpr (N == 4) asm volatile("s_waitcnt vmcnt(4)" ::: "memory");
  else if constexpr (N == 6) asm volatile("s_waitcnt vmcnt(6)" ::: "memory");
  else if constexpr (N == 8) asm volatile("s_waitcnt vmcnt(8)" ::: "memory");
  __builtin_amdgcn_sched_barrier(0);
}
#define BAR __builtin_amdgcn_s_barrier()

// ---------------- prep: 3 fp32->bf16 converts + doc_start ----------------
__global__ __launch_bounds__(256) void k_prep(const float* __restrict__ x,
                                              const float* __restrict__ qw,
                                              const float* __restrict__ cw,
                                              ushort* __restrict__ xb, ushort* __restrict__ wb,
                                              ushort* __restrict__ cbuf,
                                              const int* __restrict__ docs, int* __restrict__ dstart) {
  const int b = blockIdx.x;
  if (b < 8192) {
    const int i = b * 256 + threadIdx.x;  // float4 index over concatenated buffers
    const float* src;
    ushort* dst;
    int j;
    if (i < 1048576)       { src = x;  dst = xb;   j = i; }
    else if (i < 1835008)  { src = qw; dst = wb;   j = i - 1048576; }
    else                   { src = cw; dst = cbuf; j = i - 1835008; }
    float4 v = reinterpret_cast<const float4*>(src)[j];
    ushort4 o;
    o.x = f2bf(v.x); o.y = f2bf(v.y); o.z = f2bf(v.z); o.w = f2bf(v.w);
    reinterpret_cast<ushort4*>(dst)[j] = o;
  } else {
    const int i = (b - 8192) * 256 + threadIdx.x;
    if (i < T_SEQ) {
      int d = docs[i];
      int lo = 0, hi = i;
      while (lo < hi) { int mid = (lo + hi) >> 1; if (docs[mid] < d) lo = mid + 1; else hi = mid; }
      dstart[i] = lo;
    }
  }
}

// ---------------- QKV GEMM: C[M][N] = A[M][K]*B[N][K]^T, 32x32x16 MFMA ----------------
// BM=128 BN=384 BK=64, grid 256 (1/CU), 8 waves: wave_m=w>>2 (64 rows), wave_n=w&3 (96 cols).
// LDS: 2 bufs x [A 128 rows | B 384 rows] x 128B rows (XOR chunk swizzle), 64KB/buf.
// Staging: 8 units of 64 rows (1 load/thread each), counted vmcnt(4)/vmcnt(0) drains.
__global__ __launch_bounds__(512, 2) void k_gemm32(const ushort* __restrict__ A,
                                                   const ushort* __restrict__ B,
                                                   ushort* __restrict__ C,
                                                   int N, int K) {
  __shared__ ushort lds[2][512 * 64];   // 128KB
  const int tid = threadIdx.x;
  const int lane = tid & 63;
  const int w = tid >> 6;
  const int l5 = lane >> 5;        // k-group (0/1)
  const int lr32 = lane & 31;      // row/col within 32-frag
  const int wave_m = w >> 2, wave_n = w & 3;

  // XCD-aware bijective remap: each XCD gets 4 private A-panels x all 8 B-panels
  const int bid = blockIdx.x;
  const int s = (bid & 7) * 32 + (bid >> 3);            // 0..255, chunk of 32 per XCD
  const int m0 = ((s >> 5) * 4 + ((s >> 3) & 3)) * 128; // 32 m-tiles
  const int n0 = (s & 7) * 384;                         // 8 n-tiles

  f16v acc[2][3];
#pragma unroll
  for (int i = 0; i < 2; ++i)
#pragma unroll
    for (int j = 0; j < 3; ++j)
#pragma unroll
      for (int r = 0; r < 16; ++r) acc[i][j][r] = 0.f;

  const int NT = K >> 6;

  // stage 4 units (unit = 64 rows x 8 chunks of 16B; 1 load/thread/unit)
  auto STAGE4 = [&](int buf, int t, int ug) {
    const int k0 = t << 6;
#pragma unroll
    for (int uu = 0; uu < 4; ++uu) {
      const int u = ug * 4 + uu;
      const int row = u * 64 + (tid >> 3);              // 0..511
      const int c = (tid & 7) ^ (row & 7);              // inverse-swizzled source chunk
      const ushort* src = (u < 2) ? (A + (size_t)(m0 + row) * K + k0 + c * 8)
                                  : (B + (size_t)(n0 + row - 128) * K + k0 + c * 8);
      GLDS16(src, (char*)&lds[buf][0] + u * 8192 + w * 1024);  // + lane*16 by HW
    }
  };

  STAGE4(0, 0, 0); STAGE4(0, 0, 1);
  wait_vmcnt<0>();
  BAR;

  int cur = 0;
  for (int t = 0; t < NT; ++t) {
    const bool more = (t + 1) < NT;
    const char* bb = (const char*)&lds[cur][0];

#define RD_FRAGS(ks, a, b)                                                        \
    _Pragma("unroll") for (int mt = 0; mt < 2; ++mt) {                            \
      const int row = wave_m * 64 + mt * 32 + lr32;                               \
      a[mt] = *(const sh8*)(bb + row * 128 + ((((ks) * 2 + l5) ^ (row & 7)) * 16));\
    }                                                                             \
    _Pragma("unroll") for (int nt = 0; nt < 3; ++nt) {                            \
      const int row = 128 + wave_n * 96 + nt * 32 + lr32;                         \
      b[nt] = *(const sh8*)(bb + row * 128 + ((((ks) * 2 + l5) ^ (row & 7)) * 16));\
    }

#define MFMA6(a, b)                                                               \
    __builtin_amdgcn_s_setprio(1);                                                \
    _Pragma("unroll") for (int mt = 0; mt < 2; ++mt)                              \
    _Pragma("unroll") for (int nt = 0; nt < 3; ++nt)                              \
      acc[mt][nt] = __builtin_amdgcn_mfma_f32_32x32x16_bf16(a[mt], b[nt],         \
                                                            acc[mt][nt], 0, 0, 0);\
    __builtin_amdgcn_s_setprio(0);

    {
      sh8 a[2], b[3];
      RD_FRAGS(0, a, b)
      if (more) STAGE4(cur ^ 1, t + 1, 0);
      MFMA6(a, b)
    }
    {
      sh8 a[2], b[3];
      RD_FRAGS(1, a, b)
      if (more) STAGE4(cur ^ 1, t + 1, 1);
      MFMA6(a, b)
    }
    BAR;  // mid lockstep
    {
      sh8 a[2], b[3];
      RD_FRAGS(2, a, b)
      MFMA6(a, b)
    }
    if (more) wait_vmcnt<4>();   // units 0-3 of t+1 (issued ~2.5 phases ago)
    {
      sh8 a[2], b[3];
      RD_FRAGS(3, a, b)
      MFMA6(a, b)
    }
    if (more) wait_vmcnt<0>();   // units 4-7 of t+1
    BAR;                         // buf[cur] free for re-stage; buf[cur^1] ready
    cur ^= 1;
  }
#undef RD_FRAGS
#undef MFMA6

#pragma unroll
  for (int mt = 0; mt < 2; ++mt)
#pragma unroll
    for (int nt = 0; nt < 3; ++nt) {
      const int gcol = n0 + wave_n * 96 + nt * 32 + lr32;
#pragma unroll
      for (int r = 0; r < 16; ++r) {
        const int grow = m0 + wave_m * 64 + mt * 32 + (r & 3) + 8 * (r >> 2) + 4 * l5;
        C[(size_t)grow * N + gcol] = f2bf(acc[mt][nt][r]);
      }
    }
}

// ---------------- proj GEMM: 128x128, BK=32, 3-buffer, 32x32x16 MFMA ----------------
__global__ __launch_bounds__(256) void k_gemm2(const ushort* __restrict__ A,
                                               const ushort* __restrict__ B,
                                               float* __restrict__ C,
                                               int N, int K, int gx) {
  constexpr int BM = 128, BN = 128;
  constexpr int CHA = BM * 4;              // A 16B-chunks per K-tile (4/row, BK=32)
  constexpr int CHT = (BM + BN) * 4;
  constexpr int LPW = CHT / 256;           // 4 loads/thread/tile
  constexpr int TILEB = (BM + BN) * 64;    // 16KB

  __shared__ __attribute__((aligned(16))) char lds[3 * TILEB];

  const int tid = threadIdx.x;
  const int lane = tid & 63;
  const int w = tid >> 6;
  const int l5 = lane >> 5;
  const int lr32 = lane & 31;
  const int wm = w >> 1, wn = w & 1;

  const int nwg = gridDim.x;
  const int nb = (blockIdx.x & 7) * (nwg >> 3) + (blockIdx.x >> 3);
  const int m0 = (nb / gx) * BM;
  const int n0 = (nb % gx) * BN;

  f16v acc[2][2];
#pragma unroll
  for (int i = 0; i < 2; ++i)
#pragma unroll
    for (int j = 0; j < 2; ++j)
#pragma unroll
      for (int r = 0; r < 16; ++r) acc[i][j][r] = 0.f;

  const int NT = K >> 5;

  auto STAGE = [&](int t, int buf) {
    const int k0 = t << 5;
#pragma unroll
    for (int l = 0; l < LPW; ++l) {
      const int cb = (l * 4 + w) * 64;
      const int ch = cb + lane;
      const ushort* src;
      if (ch < CHA) {
        const int row = ch >> 2;
        const int cs = (ch & 3) ^ ((row >> 1) & 3);
        src = A + (size_t)(m0 + row) * K + k0 + cs * 8;
      } else {
        const int c2 = ch - CHA;
        const int row = c2 >> 2;
        const int cs = (c2 & 3) ^ ((row >> 1) & 3);
        src = B + (size_t)(n0 + row) * K + k0 + cs * 8;
      }
      GLDS16(src, lds + buf * TILEB + cb * 16);
    }
  };

  STAGE(0, 0);
  STAGE(1, 1);
  wait_vmcnt<LPW>();
  BAR;

  int bufc = 0;
  for (int t = 0; t < NT; ++t) {
    const bool more = (t + 2) < NT;
    if (more) STAGE(t + 2, bufc == 0 ? 2 : (bufc == 1 ? 0 : 1));

    const char* bb = lds + bufc * TILEB;
#pragma unroll
    for (int ks = 0; ks < 2; ++ks) {
      sh8 a[2], b[2];
#pragma unroll
      for (int mt = 0; mt < 2; ++mt) {
        const int row = wm * 64 + mt * 32 + lr32;
        a[mt] = *(const sh8*)(bb + row * 64 + (((ks * 2 + l5) ^ ((row >> 1) & 3)) * 16));
      }
#pragma unroll
      for (int nt = 0; nt < 2; ++nt) {
        const int row = wn * 64 + nt * 32 + lr32;
        b[nt] = *(const sh8*)(bb + BM * 64 + row * 64 + (((ks * 2 + l5) ^ ((row >> 1) & 3)) * 16));
      }
      __builtin_amdgcn_s_setprio(1);
#pragma unroll
      for (int mt = 0; mt < 2; ++mt)
#pragma unroll
        for (int nt = 0; nt < 2; ++nt)
          acc[mt][nt] = __builtin_amdgcn_mfma_f32_32x32x16_bf16(a[mt], b[nt], acc[mt][nt], 0, 0, 0);
      __builtin_amdgcn_s_setprio(0);
    }

    if (more) wait_vmcnt<LPW>();
    else      wait_vmcnt<0>();
    BAR;
    bufc = bufc == 2 ? 0 : bufc + 1;
  }

#pragma unroll
  for (int mt = 0; mt < 2; ++mt)
#pragma unroll
    for (int nt = 0; nt < 2; ++nt) {
      const int gcol = n0 + wn * 64 + nt * 32 + lr32;
#pragma unroll
      for (int r = 0; r < 16; ++r) {
        const int grow = m0 + wm * 64 + mt * 32 + (r & 3) + 8 * (r >> 2) + 4 * l5;
        C[(size_t)grow * N + gcol] = acc[mt][nt][r];
      }
    }
}

// ---------------- fused RMSNorm + rotary + V-mix (4 (t,h) pairs / block) ----------------
__global__ __launch_bounds__(256) void k_fuse(const ushort* __restrict__ qkvb,
                                              const float* __restrict__ ve,
                                              const float* __restrict__ lam,
                                              ushort* __restrict__ qh, ushort* __restrict__ kh,
                                              ushort* __restrict__ vh) {
  const int pair = blockIdx.x * 4 + (threadIdx.x >> 6);
  const int t = pair >> 3, h = pair & 7;
  const int l = threadIdx.x & 63;
  const ushort* base = qkvb + (size_t)t * NQKV + h * HDIM + 2 * l;
  uint qu = *reinterpret_cast<const uint*>(base);
  uint ku = *reinterpret_cast<const uint*>(base + 1024);
  uint vu = *reinterpret_cast<const uint*>(base + 2048);
  float q0 = bf2f((ushort)qu), q1 = bf2f((ushort)(qu >> 16));
  float k0 = bf2f((ushort)ku), k1 = bf2f((ushort)(ku >> 16));
  float v0 = bf2f((ushort)vu), v1 = bf2f((ushort)(vu >> 16));
  float sq = q0 * q0 + q1 * q1, sk = k0 * k0 + k1 * k1;
#pragma unroll
  for (int m = 1; m < 64; m <<= 1) { sq += __shfl_xor(sq, m); sk += __shfl_xor(sk, m); }
  const float eps = 1.1920928955078125e-07f;
  float rq = rsqrtf(sq * (1.f / 128.f) + eps);
  float rk = rsqrtf(sk * (1.f / 128.f) + eps);
  q0 *= rq; q1 *= rq; k0 *= rk; k1 *= rk;
  float c0 = 1.f, s0 = 0.f, c1 = 1.f, s1 = 0.f;
  if ((l & 31) < 16) {
    const int f0 = 2 * (l & 31);
    float fr0 = exp2f(-10.f * (float)f0 * (1.f / 31.f));
    float fr1 = exp2f(-10.f * (float)(f0 + 1) * (1.f / 31.f));
    sincosf((float)t * fr0, &s0, &c0);
    sincosf((float)t * fr1, &s1, &c1);
  }
  float qx0 = __shfl_xor(q0, 32), qx1 = __shfl_xor(q1, 32);
  float kx0 = __shfl_xor(k0, 32), kx1 = __shfl_xor(k1, 32);
  const float sgn = (l < 32) ? 1.f : -1.f;
  float qr0 = q0 * c0 + sgn * qx0 * s0;
  float qr1 = q1 * c1 + sgn * qx1 * s1;
  float kr0 = k0 * c0 + sgn * kx0 * s0;
  float kr1 = k1 * c1 + sgn * kx1 * s1;
  const float l0 = lam[0], l1 = lam[1];
  float2 vev = *reinterpret_cast<const float2*>(ve + (size_t)t * DIMN + h * HDIM + 2 * l);
  float vr0 = l0 * v0 + l1 * vev.x;
  float vr1 = l0 * v1 + l1 * vev.y;
  const size_t o = ((size_t)h * T_SEQ + t) * HDIM + 2 * l;
  *reinterpret_cast<uint*>(qh + o) = (uint)f2bf(qr0) | ((uint)f2bf(qr1) << 16);
  *reinterpret_cast<uint*>(kh + o) = (uint)f2bf(kr0) | ((uint)f2bf(kr1) << 16);
  *reinterpret_cast<uint*>(vh + o) = (uint)f2bf(vr0) | ((uint)f2bf(vr1) << 16);
}

// ---------------- V transpose: vh[h][t][d] -> vt[h][d][t] ----------------
__global__ __launch_bounds__(256) void k_vt(const ushort* __restrict__ vh, ushort* __restrict__ vt) {
  const int tb = blockIdx.x, db = blockIdx.y, h = blockIdx.z;
  __shared__ ushort L[64][68];
  const int tid = threadIdx.x;
  const int t0 = tb * 64, d0 = db * 64;
  const size_t ib = ((size_t)h * T_SEQ + t0) * HDIM + d0;
#pragma unroll
  for (int p = 0; p < 4; ++p) {
    const int row = p * 16 + (tid >> 4);
    const int c4 = (tid & 15) * 4;
    ushort4 v = *reinterpret_cast<const ushort4*>(vh + ib + (size_t)row * HDIM + c4);
    *reinterpret_cast<ushort4*>(&L[row][c4]) = v;
  }
  __syncthreads();
  const size_t ob = ((size_t)h * HDIM + d0) * T_SEQ + t0;
#pragma unroll
  for (int p = 0; p < 4; ++p) {
    const int drow = p * 16 + (tid >> 4);
    const int t4 = (tid & 15) * 4;
    ushort4 v;
    v.x = L[t4 + 0][drow]; v.y = L[t4 + 1][drow];
    v.z = L[t4 + 2][drow]; v.w = L[t4 + 3][drow];
    *reinterpret_cast<ushort4*>(vt + ob + (size_t)drow * T_SEQ + t4) = v;
  }
}

// ---------------- flash attention: 4 waves, 64 q-rows, LDS-staged KV ----------------
__global__ __launch_bounds__(256) void k_attn(const ushort* __restrict__ qh,
                                              const ushort* __restrict__ kh,
                                              const ushort* __restrict__ vt,
                                              const int* __restrict__ doc_start,
                                              ushort* __restrict__ y) {
  const int h  = blockIdx.x;
  const int qb = blockIdx.y;
  const int q0 = qb * 64;
  const int tid  = threadIdx.x;
  const int wave = tid >> 6;
  const int lane = tid & 63;
  const int lr = lane & 15, lg = lane >> 4;

  __shared__ ushort Ks[2][64 * 128];
  __shared__ ushort Vs[2][128 * 64];
  __shared__ ushort Ps[4][16 * 64];

  const ushort* Kg = kh + (size_t)h * T_SEQ * HDIM;
  const ushort* Vg = vt + (size_t)h * HDIM * T_SEQ;

  const int i_me = q0 + wave * 16 + lr;
  sh8 qf[4];
  {
    const ushort* qp = qh + ((size_t)h * T_SEQ + i_me) * HDIM + lg * 8;
#pragma unroll
    for (int c = 0; c < 4; ++c) qf[c] = *reinterpret_cast<const sh8*>(qp + c * 32);
  }
  const int ds_me = doc_start[i_me];
  const int ds_hi = doc_start[q0 + 63];
  const int kb0   = doc_start[q0] >> 6;

  const f4 fzero = {0.f, 0.f, 0.f, 0.f};
  f4 o_acc[8];
#pragma unroll
  for (int i = 0; i < 8; ++i) o_acc[i] = fzero;
  float m_me = -1e30f, l_me = 0.f;

  auto STAGE = [&](int b, int k0) {
#pragma unroll
    for (int p = 0; p < 4; ++p) {
      const int c = p * 256 + tid;
      const int row = c >> 4, cc = c & 15;
      GLDS16(Kg + (size_t)(k0 + row) * HDIM + (cc ^ (row & 7)) * 8,
             &Ks[b][(p * 256 + wave * 64) * 8]);
    }
#pragma unroll
    for (int p = 0; p < 4; ++p) {
      const int c = p * 256 + tid;
      const int d = c >> 3, cc = c & 7;
      GLDS16(Vg + (size_t)d * T_SEQ + k0 + (cc ^ (d & 7)) * 8,
             &Vs[b][(p * 256 + wave * 64) * 8]);
    }
  };

  int cur = 0;
  STAGE(0, kb0 * 64);

  const int sw = (lr & 7) << 4;

  for (int kb = kb0; kb <= qb; ++kb) {
    const int k0 = kb * 64;
    __syncthreads();
    if (kb < qb) STAGE(cur ^ 1, k0 + 64);

    const char* Kb = (const char*)&Ks[cur][0];
    const char* Vb = (const char*)&Vs[cur][0];
    char* Pw = (char*)&Ps[wave][0];

    f4 sacc[4];
#pragma unroll
    for (int jt = 0; jt < 4; ++jt) sacc[jt] = fzero;
#pragma unroll
    for (int jt = 0; jt < 4; ++jt)
#pragma unroll
      for (int c = 0; c < 4; ++c) {
        sh8 kf = *reinterpret_cast<const sh8*>(Kb + (jt * 16 + lr) * 256 + ((c * 64 + lg * 16) ^ sw));
        sacc[jt] = __builtin_amdgcn_mfma_f32_16x16x32_bf16(kf, qf[c], sacc[jt], 0, 0, 0);
      }

    const bool fullblk = (kb < qb) && (ds_hi <= k0);
    float p[4][4];
#pragma unroll
    for (int jt = 0; jt < 4; ++jt)
#pragma unroll
      for (int r = 0; r < 4; ++r) {
        float s = sacc[jt][r] * ATTN_SCALE;
        const int j = k0 + jt * 16 + lg * 4 + r;
        bool valid = fullblk || ((j <= i_me) && (j >= ds_me));
        p[jt][r] = valid ? s : -1e30f;
      }
    float tm = -1e30f;
#pragma unroll
    for (int jt = 0; jt < 4; ++jt) {
      float a = fmaxf(p[jt][0], p[jt][1]), b = fmaxf(p[jt][2], p[jt][3]);
      tm = fmaxf(tm, fmaxf(a, b));
    }
    tm = fmaxf(tm, __shfl_xor(tm, 16));
    tm = fmaxf(tm, __shfl_xor(tm, 32));
    const float mnew = fmaxf(m_me, tm);
    const float sc = __expf(m_me - mnew);
    m_me = mnew;
    float rs = 0.f;
#pragma unroll
    for (int jt = 0; jt < 4; ++jt)
#pragma unroll
      for (int r = 0; r < 4; ++r) {
        float pv = __expf(p[jt][r] - mnew);
        p[jt][r] = pv;
        rs += pv;
      }
    rs += __shfl_xor(rs, 16);
    rs += __shfl_xor(rs, 32);
    l_me = l_me * sc + rs;

#pragma unroll
    for (int jt = 0; jt < 4; ++jt) {
      uint2 u;
      u.x = (uint)f2bf(p[jt][0]) | ((uint)f2bf(p[jt][1]) << 16);
      u.y = (uint)f2bf(p[jt][2]) | ((uint)f2bf(p[jt][3]) << 16);
      *reinterpret_cast<uint2*>(Pw + lr * 128 + ((jt * 32 + lg * 8) ^ sw)) = u;
    }

    float sco[4];
#pragma unroll
    for (int rr = 0; rr < 4; ++rr) sco[rr] = __shfl(sc, lg * 4 + rr);
#pragma unroll
    for (int dt = 0; dt < 8; ++dt)
#pragma unroll
      for (int rr = 0; rr < 4; ++rr) o_acc[dt][rr] *= sco[rr];

#pragma unroll
    for (int ks = 0; ks < 2; ++ks) {
      sh8 pa = *reinterpret_cast<const sh8*>(Pw + lr * 128 + ((ks * 64 + lg * 16) ^ sw));
#pragma unroll
      for (int dt = 0; dt < 8; ++dt) {
        sh8 vf = *reinterpret_cast<const sh8*>(Vb + (dt * 16 + lr) * 128 + ((ks * 64 + lg * 16) ^ sw));
        o_acc[dt] = __builtin_amdgcn_mfma_f32_16x16x32_bf16(pa, vf, o_acc[dt], 0, 0, 0);
      }
    }

    __builtin_amdgcn_s_barrier();
    cur ^= 1;
  }

  float lo[4];
#pragma unroll
  for (int rr = 0; rr < 4; ++rr) lo[rr] = __shfl(l_me, lg * 4 + rr);
#pragma unroll
  for (int dt = 0; dt < 8; ++dt)
#pragma unroll
    for (int rr = 0; rr < 4; ++rr) {
      const int trow = q0 + wave * 16 + lg * 4 + rr;
      y[(size_t)trow * DIMN + h * HDIM + dt * 16 + lr] = f2bf(o_acc[dt][rr] / lo[rr]);
    }
}

extern "C" void kernel_launch(void* const* d_in, const int* in_sizes, int n_in,
                              void* d_out, int out_size, void* d_ws, size_t ws_size,
                              hipStream_t stream) {
  const float* x    = (const float*)d_in[0];
  const float* ve   = (const float*)d_in[1];
  const float* qkvw = (const float*)d_in[2];
  const float* lam  = (const float*)d_in[3];
  const float* cpw  = (const float*)d_in[4];
  const int*   docs = (const int*)d_in[5];
  float* out = (float*)d_out;
  char* ws = (char*)d_ws;

  ushort* qkvb = (ushort*)(ws);                    // 24MB  [0,24)
  ushort* xb   = (ushort*)(ws + (24ull << 20));    // 8MB   [24,32)
  ushort* wb   = (ushort*)(ws + (32ull << 20));    // 6MB   [32,38)
  ushort* cb   = (ushort*)(ws + (38ull << 20));    // 2MB   [38,40)
  ushort* qh   = (ushort*)(ws + (40ull << 20));    // 8MB   [40,48)
  ushort* kh   = (ushort*)(ws + (48ull << 20));    // 8MB   [48,56)
  ushort* vh   = (ushort*)(ws + (56ull << 20));    // 8MB   [56,64)
  ushort* vt   = (ushort*)(ws + (64ull << 20));    // 8MB   [64,72)
  ushort* yb   = (ushort*)(ws + (72ull << 20));    // 8MB   [72,80)
  int*  dstart = (int*)(ws + (80ull << 20));       // 16KB

  k_prep<<<8192 + 16, 256, 0, stream>>>(x, qkvw, cpw, xb, wb, cb, docs, dstart);

  // QKV: M=4096, N=3072, K=1024 — 128x384 tiles, grid 32x8 = 256 = 1/CU
  k_gemm32<<<256, 512, 0, stream>>>(xb, wb, qkvb, NQKV, DIMN);

  k_fuse<<<T_SEQ * NH / 4, 256, 0, stream>>>(qkvb, ve, lam, qh, kh, vh);
  k_vt<<<dim3(T_SEQ / 64, HDIM / 64, NH), 256, 0, stream>>>(vh, vt);

  k_attn<<<dim3(NH, T_SEQ / 64), 256, 0, stream>>>(qh, kh, vt, dstart, yb);

  // proj: M=4096, N=1024, K=1024 — 128x128 tile, grid 32x8=256 (%8==0)
  k_gemm2<<<256, 256, 0, stream>>>(yb, cb, out, DIMN, DIMN, DIMN / 128);
}